// Round 4
// baseline (1218.925 us; speedup 1.0000x reference)
//
#include <hip/hip_runtime.h>
#include <hip/hip_bf16.h>
#include <math.h>
#include <stdint.h>

typedef __hip_bfloat16 bf16;

#define T_TOK 2048
#define H_DIM 1024
#define E_NUM 32
#define I_DIM 256
#define O_DIM 512
#define CAP   2048
#define TT    16
#define WT    16

__device__ __forceinline__ float b2f(bf16 v) { return __bfloat162float(v); }

// mode-dispatched element load: BF=1 -> bf16 array, BF=0 -> fp32 array
template<int BF>
__device__ __forceinline__ float ld(const void* p, size_t i) {
    if (BF) return b2f(((const bf16*)p)[i]);
    else    return ((const float*)p)[i];
}

// ---------------------------------------------------------------------------
// Kernel 0: dtype detector (evidence so far says fp32, but keep the insurance).
// ---------------------------------------------------------------------------
__global__ void detect_kernel(const uint32_t* __restrict__ xw, int* __restrict__ flag)
{
    if (threadIdx.x == 0 && blockIdx.x == 0) {
        int cnt = 0;
        for (int i = 0; i < 1024; ++i) {
            uint32_t w = xw[i];
            int e = (w >> 7) & 0xFF;
            if (e >= 110 && e <= 140) cnt++;
        }
        *flag = (cnt > 512) ? 1 : 0;   // 1 = bf16 inputs, 0 = fp32 inputs
    }
}

// ---------------------------------------------------------------------------
// Kernel 0b: zero the z accumulator (fp32 mode: z = d_out itself) + counts.
// ---------------------------------------------------------------------------
__global__ __launch_bounds__(256) void zero_kernel(
    float* __restrict__ z_fp32, float* __restrict__ z_bf16,
    const int* __restrict__ flag, int* __restrict__ counts)
{
    float* base = (*flag) ? z_bf16 : z_fp32;
    size_t i = (size_t)blockIdx.x * 256 + threadIdx.x;
    ((float4*)base)[i] = make_float4(0.f, 0.f, 0.f, 0.f);
    if (blockIdx.x == 0 && threadIdx.x < E_NUM) counts[threadIdx.x] = 0;
}

// ---------------------------------------------------------------------------
// Kernel 1: router. CORRECTED constants: R_O=2, G_O=2 -> S=8 experts/shard,
// 4 shards total; group g owns shards {2g, 2g+1}; keep argmax shard (of 2,
// by sum of its 8 logits, first-max), then top-2 of that shard's 8 experts.
// ---------------------------------------------------------------------------
template<int BF>
__device__ void router_body(const void* __restrict__ x, const void* __restrict__ Wr,
                            void* __restrict__ out_base,
                            int* __restrict__ counts, int* __restrict__ tok_list,
                            float* __restrict__ wt_list)
{
    int t    = blockIdx.x;
    int lane = threadIdx.x;
    int e    = lane & 31;
    int half = lane >> 5;

    float acc = 0.f;
    size_t xoff = (size_t)t * H_DIM;
    int h0 = half * (H_DIM / 2);
    for (int h = h0; h < h0 + H_DIM / 2; ++h)
        acc = fmaf(ld<BF>(x, xoff + h), ld<BF>(Wr, (size_t)h * E_NUM + e), acc);
    acc += __shfl_down(acc, 32);

    __shared__ float sl[E_NUM];
    if (lane < 32) {
        sl[e] = acc;
        size_t li = (size_t)T_TOK * H_DIM + (size_t)t * E_NUM + e;
        if (BF) ((bf16*)out_base)[li] = __float2bfloat16(acc);
        else    ((float*)out_base)[li] = acc;
    }
    __syncthreads();

    if (lane == 0) {
        float s[E_NUM];
        #pragma unroll
        for (int i = 0; i < E_NUM; ++i) s[i] = sl[i];

        int   selE[4];
        float selL[4];
        int ns = 0;
        for (int g = 0; g < 2; ++g) {
            // two shards per group, 8 experts each: sh = 2g, 2g+1
            float sum0 = 0.f, sum1 = 0.f;
            #pragma unroll
            for (int j = 0; j < 8; ++j) {
                sum0 += s[(2*g)   * 8 + j];
                sum1 += s[(2*g+1) * 8 + j];
            }
            int bestSh = (sum1 > sum0) ? (2*g+1) : (2*g);   // first max on tie
            int base = bestSh * 8;
            int i1 = 0;
            for (int j = 1; j < 8; ++j) if (s[base+j] > s[base+i1]) i1 = j;
            int i2 = -1;
            for (int j = 0; j < 8; ++j) {
                if (j == i1) continue;
                if (i2 < 0 || s[base+j] > s[base+i2]) i2 = j;
            }
            selE[ns] = base + i1; selL[ns] = s[base+i1]; ++ns;
            selE[ns] = base + i2; selL[ns] = s[base+i2]; ++ns;
        }
        float m = fmaxf(fmaxf(selL[0], selL[1]), fmaxf(selL[2], selL[3]));
        float w[4];
        float sum = 0.f;
        for (int j = 0; j < 4; ++j) { w[j] = expf(selL[j] - m); sum += w[j]; }
        float inv = 1.f / sum;
        for (int j = 0; j < 4; ++j) {
            int ee = selE[j];
            int pos = atomicAdd(&counts[ee], 1);
            if (pos >= 0 && pos < CAP) {
                tok_list[ee * CAP + pos] = t;
                wt_list[ee * CAP + pos]  = w[j] * inv;
            }
        }
    }
}

__global__ __launch_bounds__(64) void router_kernel(
    const void* x, const void* Wr, void* out_base, const int* flag,
    int* counts, int* tok_list, float* wt_list)
{
    if (*flag) router_body<1>(x, Wr, out_base, counts, tok_list, wt_list);
    else       router_body<0>(x, Wr, out_base, counts, tok_list, wt_list);
}

// ---------------------------------------------------------------------------
// Kernel 2: grouped expert MLP, atomic fp32 accumulate into z.
// LDS: xs[16][1024] fp32 = 64KB exactly; hs overlaid on xs after gate/up.
// ---------------------------------------------------------------------------
template<int BF>
__device__ void expert_body(const void* __restrict__ x,
                            const void* __restrict__ Wg, const void* __restrict__ Wu,
                            const void* __restrict__ Wd,
                            const int* __restrict__ counts, const int* __restrict__ tok_list,
                            const float* __restrict__ wt_list,
                            float* __restrict__ z)
{
    int e = blockIdx.x;
    int n = counts[e];
    n = n < 0 ? 0 : (n > CAP ? CAP : n);
    int t0 = blockIdx.y * TT;
    if (t0 >= n) return;
    int tid = threadIdx.x;

    __shared__ __align__(16) float xs[TT][H_DIM];          // 64 KB exactly
    float (*hs)[I_DIM] = reinterpret_cast<float(*)[I_DIM]>(&xs[0][0]);  // overlay

    const int*   tl = tok_list + e * CAP;
    const float* wl = wt_list  + e * CAP;

    for (int idx = tid; idx < TT * H_DIM; idx += 256) {
        int tt = idx >> 10;
        int h  = idx & (H_DIM - 1);
        int it = t0 + tt;
        int tkn = (it < n) ? tl[it] : tl[t0];
        tkn = (tkn < 0) ? 0 : (tkn >= T_TOK ? T_TOK - 1 : tkn);
        xs[tt][h] = ld<BF>(x, (size_t)tkn * H_DIM + h);
    }
    __syncthreads();

    // ---- gate/up projections: intermediate column = tid ----
    size_t wbase = (size_t)e * H_DIM * I_DIM + tid;
    float ag[TT], au[TT];
    #pragma unroll
    for (int tt = 0; tt < TT; ++tt) { ag[tt] = 0.f; au[tt] = 0.f; }

    for (int k = 0; k < H_DIM; k += 4) {
        float g0 = ld<BF>(Wg, wbase + (size_t)(k+0) * I_DIM);
        float g1 = ld<BF>(Wg, wbase + (size_t)(k+1) * I_DIM);
        float g2 = ld<BF>(Wg, wbase + (size_t)(k+2) * I_DIM);
        float g3 = ld<BF>(Wg, wbase + (size_t)(k+3) * I_DIM);
        float u0 = ld<BF>(Wu, wbase + (size_t)(k+0) * I_DIM);
        float u1 = ld<BF>(Wu, wbase + (size_t)(k+1) * I_DIM);
        float u2 = ld<BF>(Wu, wbase + (size_t)(k+2) * I_DIM);
        float u3 = ld<BF>(Wu, wbase + (size_t)(k+3) * I_DIM);
        #pragma unroll
        for (int tt = 0; tt < TT; ++tt) {
            float4 xv = *(const float4*)&xs[tt][k];
            ag[tt] = fmaf(xv.w, g3, fmaf(xv.z, g2, fmaf(xv.y, g1, fmaf(xv.x, g0, ag[tt]))));
            au[tt] = fmaf(xv.w, u3, fmaf(xv.z, u2, fmaf(xv.y, u1, fmaf(xv.x, u0, au[tt]))));
        }
    }
    float hval[TT];
    #pragma unroll
    for (int tt = 0; tt < TT; ++tt) {
        float g = ag[tt];
        hval[tt] = (g / (1.f + expf(-g))) * au[tt];   // silu(g) * up
    }
    __syncthreads();            // everyone done READING xs
    #pragma unroll
    for (int tt = 0; tt < TT; ++tt) hs[tt][tid] = hval[tt];
    __syncthreads();            // hs visible

    // ---- down projection: output columns tid and tid+256 ----
    size_t dbase = (size_t)e * I_DIM * O_DIM;
    float y0[TT], y1[TT];
    #pragma unroll
    for (int tt = 0; tt < TT; ++tt) { y0[tt] = 0.f; y1[tt] = 0.f; }

    for (int k = 0; k < I_DIM; k += 4) {
        float d00 = ld<BF>(Wd, dbase + (size_t)(k+0) * O_DIM + tid);
        float d01 = ld<BF>(Wd, dbase + (size_t)(k+1) * O_DIM + tid);
        float d02 = ld<BF>(Wd, dbase + (size_t)(k+2) * O_DIM + tid);
        float d03 = ld<BF>(Wd, dbase + (size_t)(k+3) * O_DIM + tid);
        float d10 = ld<BF>(Wd, dbase + (size_t)(k+0) * O_DIM + tid + 256);
        float d11 = ld<BF>(Wd, dbase + (size_t)(k+1) * O_DIM + tid + 256);
        float d12 = ld<BF>(Wd, dbase + (size_t)(k+2) * O_DIM + tid + 256);
        float d13 = ld<BF>(Wd, dbase + (size_t)(k+3) * O_DIM + tid + 256);
        #pragma unroll
        for (int tt = 0; tt < TT; ++tt) {
            float4 hv = *(const float4*)&hs[tt][k];
            y0[tt] = fmaf(hv.w, d03, fmaf(hv.z, d02, fmaf(hv.y, d01, fmaf(hv.x, d00, y0[tt]))));
            y1[tt] = fmaf(hv.w, d13, fmaf(hv.z, d12, fmaf(hv.y, d11, fmaf(hv.x, d10, y1[tt]))));
        }
    }

    int gsel = e >> 4;    // experts 0..15 -> cols [0,512), 16..31 -> [512,1024)
    size_t colbase = (size_t)gsel * O_DIM;
    #pragma unroll
    for (int tt = 0; tt < TT; ++tt) {
        int it = t0 + tt;
        if (it < n) {
            float w  = wl[it];
            int tkn = tl[it];
            tkn = (tkn < 0) ? 0 : (tkn >= T_TOK ? T_TOK - 1 : tkn);
            atomicAdd(&z[(size_t)tkn * H_DIM + colbase + tid],       w * y0[tt]);
            atomicAdd(&z[(size_t)tkn * H_DIM + colbase + tid + 256], w * y1[tt]);
        }
    }
}

__global__ __launch_bounds__(256) void expert_kernel(
    const void* x, const void* Wg, const void* Wu, const void* Wd,
    const int* flag, const int* counts, const int* tok_list, const float* wt_list,
    float* z_fp32, float* z_bf16)
{
    if (*flag) expert_body<1>(x, Wg, Wu, Wd, counts, tok_list, wt_list, z_bf16);
    else       expert_body<0>(x, Wg, Wu, Wd, counts, tok_list, wt_list, z_fp32);
}

// ---------------------------------------------------------------------------
// Kernel 3: out = z @ Wc, in-place safe (block owns its 16 rows).
// ---------------------------------------------------------------------------
template<int BF>
__device__ void wc_body(const float* __restrict__ z, const void* __restrict__ Wc,
                        void* __restrict__ out_base)
{
    int t0  = blockIdx.x * WT;
    int tid = threadIdx.x;

    __shared__ __align__(16) float ps[WT][H_DIM];   // 64 KB exactly
    for (int idx = tid; idx < WT * H_DIM; idx += 256) {
        int tt = idx >> 10;
        int h  = idx & (H_DIM - 1);
        ps[tt][h] = z[(size_t)(t0 + tt) * H_DIM + h];
    }
    __syncthreads();

    float acc[WT][4];
    #pragma unroll
    for (int tt = 0; tt < WT; ++tt)
        #pragma unroll
        for (int q = 0; q < 4; ++q) acc[tt][q] = 0.f;

    for (int k = 0; k < H_DIM; k += 2) {
        float c00 = ld<BF>(Wc, (size_t)(k+0) * H_DIM + tid);
        float c01 = ld<BF>(Wc, (size_t)(k+0) * H_DIM + tid + 256);
        float c02 = ld<BF>(Wc, (size_t)(k+0) * H_DIM + tid + 512);
        float c03 = ld<BF>(Wc, (size_t)(k+0) * H_DIM + tid + 768);
        float c10 = ld<BF>(Wc, (size_t)(k+1) * H_DIM + tid);
        float c11 = ld<BF>(Wc, (size_t)(k+1) * H_DIM + tid + 256);
        float c12 = ld<BF>(Wc, (size_t)(k+1) * H_DIM + tid + 512);
        float c13 = ld<BF>(Wc, (size_t)(k+1) * H_DIM + tid + 768);
        #pragma unroll
        for (int tt = 0; tt < WT; ++tt) {
            float2 pv = *(const float2*)&ps[tt][k];
            acc[tt][0] = fmaf(pv.y, c10, fmaf(pv.x, c00, acc[tt][0]));
            acc[tt][1] = fmaf(pv.y, c11, fmaf(pv.x, c01, acc[tt][1]));
            acc[tt][2] = fmaf(pv.y, c12, fmaf(pv.x, c02, acc[tt][2]));
            acc[tt][3] = fmaf(pv.y, c13, fmaf(pv.x, c03, acc[tt][3]));
        }
    }

    #pragma unroll
    for (int tt = 0; tt < WT; ++tt) {
        #pragma unroll
        for (int q = 0; q < 4; ++q) {
            size_t o = (size_t)(t0 + tt) * H_DIM + tid + 256 * q;
            if (BF) ((bf16*)out_base)[o] = __float2bfloat16(acc[tt][q]);
            else    ((float*)out_base)[o] = acc[tt][q];
        }
    }
}

__global__ __launch_bounds__(256) void wc_kernel(
    const float* z_fp32, const float* z_bf16, const void* Wc,
    void* out_base, const int* flag)
{
    if (*flag) wc_body<1>(z_bf16, Wc, out_base);
    else       wc_body<0>(z_fp32, Wc, out_base);
}

// ---------------------------------------------------------------------------
extern "C" void kernel_launch(void* const* d_in, const int* in_sizes, int n_in,
                              void* d_out, int out_size, void* d_ws, size_t ws_size,
                              hipStream_t stream)
{
    (void)in_sizes; (void)n_in; (void)out_size; (void)ws_size;

    const void* x  = d_in[0];
    const void* Wr = d_in[1];
    const void* Wg = d_in[2];
    const void* Wu = d_in[3];
    const void* Wd = d_in[4];
    const void* Wc = d_in[5];

    // ws layout: counts[32] @0, flag @128, tok_list @4096 (256KB),
    // wt_list after (256KB); bf16-mode z scratch @1MB (8MB, dead path).
    char* ws = (char*)d_ws;
    int*   counts   = (int*)(ws + 0);
    int*   flag     = (int*)(ws + 128);
    int*   tok_list = (int*)(ws + 4096);
    float* wt_list  = (float*)(ws + 4096 + (size_t)E_NUM * CAP * 4);
    float* z_bf16   = (float*)(ws + (1u << 20));

    float* z_fp32 = (float*)d_out;   // fp32 mode: accumulate in the output region

    detect_kernel<<<1, 64, 0, stream>>>((const uint32_t*)x, flag);
    zero_kernel<<<T_TOK, 256, 0, stream>>>(z_fp32, z_bf16, flag, counts);
    router_kernel<<<T_TOK, 64, 0, stream>>>(x, Wr, d_out, flag, counts, tok_list, wt_list);
    expert_kernel<<<dim3(E_NUM, T_TOK / TT), 256, 0, stream>>>(
        x, Wg, Wu, Wd, flag, counts, tok_list, wt_list, z_fp32, z_bf16);
    wc_kernel<<<T_TOK / WT, 256, 0, stream>>>(z_fp32, z_bf16, Wc, d_out, flag);
}

// Round 5
// 367.748 us; speedup vs baseline: 3.3146x; 3.3146x over previous
//
#include <hip/hip_runtime.h>
#include <hip/hip_bf16.h>
#include <math.h>
#include <stdint.h>

typedef __hip_bfloat16 hbf16;

#define T_TOK 2048
#define H_DIM 1024
#define E_NUM 32
#define I_DIM 256
#define O_DIM 512
#define CAP   2048
#define TT    16
#define WT    16
#define XS    80    // padded LDS row stride (ushort elems) for A-staging

typedef __bf16 bf16x8 __attribute__((ext_vector_type(8)));
typedef float  f32x4  __attribute__((ext_vector_type(4)));

__device__ __forceinline__ float b2f(hbf16 v) { return __bfloat162float(v); }

// fp32 -> bf16 bits, round-to-nearest-even
__device__ __forceinline__ ushort f2b(float f) {
    uint32_t u = __float_as_uint(f);
    uint32_t r = (u + 0x7FFFu + ((u >> 16) & 1u)) >> 16;
    return (ushort)r;
}

template<int BF>
__device__ __forceinline__ float ld(const void* p, size_t i) {
    if (BF) return b2f(((const hbf16*)p)[i]);
    else    return ((const float*)p)[i];
}

__device__ __forceinline__ f32x4 mfma_bf16(bf16x8 a, bf16x8 b, f32x4 c) {
    return __builtin_amdgcn_mfma_f32_16x16x32_bf16(a, b, c, 0, 0, 0);
}

// ---------------------------------------------------------------------------
// dtype detector (runtime flag: 1 = bf16 inputs, 0 = fp32 inputs)
// ---------------------------------------------------------------------------
__global__ void detect_kernel(const uint32_t* __restrict__ xw, int* __restrict__ flag)
{
    if (threadIdx.x == 0 && blockIdx.x == 0) {
        int cnt = 0;
        for (int i = 0; i < 1024; ++i) {
            uint32_t w = xw[i];
            int e = (w >> 7) & 0xFF;
            if (e >= 110 && e <= 140) cnt++;
        }
        *flag = (cnt > 512) ? 1 : 0;
    }
}

// ===========================================================================
// ===============  FAST PATH (requires ws_size >= 58 MB)  ===================
// ===========================================================================

// zero z (fp32, 8MB in ws) + counts
__global__ __launch_bounds__(256) void zero_fast_kernel(
    float* __restrict__ z, int* __restrict__ counts)
{
    size_t i = (size_t)blockIdx.x * 256 + threadIdx.x;
    ((float4*)z)[i] = make_float4(0.f, 0.f, 0.f, 0.f);
    if (blockIdx.x == 0 && threadIdx.x < E_NUM) counts[threadIdx.x] = 0;
}

// Transpose+convert: src [e][K][N] (fp32 or bf16 per flag) -> dst [e][N][K] bf16
// grid.x = E*(K/32)*(N/32), block 256
__global__ __launch_bounds__(256) void convert_t_kernel(
    const void* __restrict__ src, ushort* __restrict__ dst,
    const int* __restrict__ flag, int K, int N)
{
    int bf = *flag;
    int tilesN = N >> 5, tilesK = K >> 5;
    int b  = blockIdx.x;
    int e  = b / (tilesK * tilesN);
    int r  = b % (tilesK * tilesN);
    int k0 = (r / tilesN) << 5;
    int n0 = (r % tilesN) << 5;
    size_t base = (size_t)e * K * N;
    __shared__ float sh[32][33];
    int tid = threadIdx.x;
    #pragma unroll
    for (int it = 0; it < 4; ++it) {
        int idx = tid + it * 256;
        int rr = idx >> 5, cc = idx & 31;
        size_t si = base + (size_t)(k0 + rr) * N + n0 + cc;
        sh[rr][cc] = bf ? b2f(((const hbf16*)src)[si]) : ((const float*)src)[si];
    }
    __syncthreads();
    #pragma unroll
    for (int it = 0; it < 4; ++it) {
        int idx = tid + it * 256;
        int rr = idx >> 5, cc = idx & 31;   // rr = n offset, cc = k offset
        dst[base + (size_t)(n0 + rr) * K + k0 + cc] = f2b(sh[cc][rr]);
    }
}

// ---------------------------------------------------------------------------
// Fast router: 8 tokens/block, 256 threads (8 tok x 32 experts). fp32 math.
// ---------------------------------------------------------------------------
template<int BF>
__device__ void router_fast_body(const void* __restrict__ x, const void* __restrict__ Wr,
                                 void* __restrict__ out_base,
                                 int* __restrict__ counts, int* __restrict__ tok_list,
                                 float* __restrict__ wt_list)
{
    __shared__ float xs[8][1024];
    __shared__ float sl[8][32];
    int tid = threadIdx.x;
    int t0  = blockIdx.x * 8;

    for (int idx = tid; idx < 8 * 1024; idx += 256) {
        int tr = idx >> 10, h = idx & 1023;
        xs[tr][h] = ld<BF>(x, (size_t)(t0 + tr) * H_DIM + h);
    }
    __syncthreads();

    int tokr = tid >> 5, e = tid & 31;
    float acc = 0.f;
    for (int h = 0; h < H_DIM; h += 4) {
        float4 xv = *(const float4*)&xs[tokr][h];
        float w0 = ld<BF>(Wr, (size_t)(h+0) * E_NUM + e);
        float w1 = ld<BF>(Wr, (size_t)(h+1) * E_NUM + e);
        float w2 = ld<BF>(Wr, (size_t)(h+2) * E_NUM + e);
        float w3 = ld<BF>(Wr, (size_t)(h+3) * E_NUM + e);
        acc = fmaf(xv.w, w3, fmaf(xv.z, w2, fmaf(xv.y, w1, fmaf(xv.x, w0, acc))));
    }
    sl[tokr][e] = acc;
    size_t li = (size_t)T_TOK * H_DIM + (size_t)(t0 + tokr) * E_NUM + e;
    if (BF) ((hbf16*)out_base)[li] = __float2bfloat16(acc);
    else    ((float*)out_base)[li] = acc;
    __syncthreads();

    if (tid < 8) {
        int t = t0 + tid;
        float s[E_NUM];
        #pragma unroll
        for (int i = 0; i < E_NUM; ++i) s[i] = sl[tid][i];

        int   selE[4];
        float selL[4];
        int ns = 0;
        for (int g = 0; g < 2; ++g) {
            float sum0 = 0.f, sum1 = 0.f;
            #pragma unroll
            for (int j = 0; j < 8; ++j) {
                sum0 += s[(2*g)   * 8 + j];
                sum1 += s[(2*g+1) * 8 + j];
            }
            int bestSh = (sum1 > sum0) ? (2*g+1) : (2*g);
            int base = bestSh * 8;
            int i1 = 0;
            for (int j = 1; j < 8; ++j) if (s[base+j] > s[base+i1]) i1 = j;
            int i2 = -1;
            for (int j = 0; j < 8; ++j) {
                if (j == i1) continue;
                if (i2 < 0 || s[base+j] > s[base+i2]) i2 = j;
            }
            selE[ns] = base + i1; selL[ns] = s[base+i1]; ++ns;
            selE[ns] = base + i2; selL[ns] = s[base+i2]; ++ns;
        }
        float m = fmaxf(fmaxf(selL[0], selL[1]), fmaxf(selL[2], selL[3]));
        float w[4];
        float sum = 0.f;
        for (int j = 0; j < 4; ++j) { w[j] = expf(selL[j] - m); sum += w[j]; }
        float inv = 1.f / sum;
        for (int j = 0; j < 4; ++j) {
            int ee = selE[j];
            int pos = atomicAdd(&counts[ee], 1);
            if (pos >= 0 && pos < CAP) {
                tok_list[ee * CAP + pos] = t;
                wt_list[ee * CAP + pos]  = w[j] * inv;
            }
        }
    }
}

__global__ __launch_bounds__(256) void router_fast_kernel(
    const void* x, const void* Wr, void* out_base, const int* flag,
    int* counts, int* tok_list, float* wt_list)
{
    if (*flag) router_fast_body<1>(x, Wr, out_base, counts, tok_list, wt_list);
    else       router_fast_body<0>(x, Wr, out_base, counts, tok_list, wt_list);
}

// ---------------------------------------------------------------------------
// MFMA expert kernel: 32 tokens/block, 256 thr (4 waves).
// gate/up: M=32,N=256,K=1024; down: M=32,N=512,K=256. bf16 MFMA, fp32 acc.
// A (tokens) staged fp32->bf16 in double-buffered LDS; B from pre-converted
// K-contiguous bf16 weights in ws (L2-resident).
// ---------------------------------------------------------------------------
template<int BF>
__device__ void expert_mfma_body(const void* __restrict__ x,
    const ushort* __restrict__ Wg_t, const ushort* __restrict__ Wu_t,
    const ushort* __restrict__ Wd_t,
    const int* __restrict__ counts, const int* __restrict__ tok_list,
    const float* __restrict__ wt_list, float* __restrict__ z)
{
    int e = blockIdx.x;
    int n = counts[e]; n = n < 0 ? 0 : (n > CAP ? CAP : n);
    int t0 = blockIdx.y * 32;
    if (t0 >= n) return;
    int tid  = threadIdx.x;
    int lane = tid & 63, w = tid >> 6;
    int q = lane >> 4, l15 = lane & 15;

    __shared__ ushort xA[2][32 * XS];      // 10 KB
    __shared__ ushort hsm[32 * 264];       // ~16.5 KB, padded stride 264
    __shared__ int    tokid[32];
    __shared__ float  twt[32];

    if (tid < 32) {
        int it = t0 + tid;
        int tk; float ww;
        if (it < n) { tk = tok_list[e*CAP + it]; ww = wt_list[e*CAP + it]; }
        else        { tk = tok_list[e*CAP + t0]; ww = 0.f; }
        tk = tk < 0 ? 0 : (tk >= T_TOK ? T_TOK - 1 : tk);
        tokid[tid] = tk; twt[tid] = ww;
    }
    __syncthreads();

    int stok = tid >> 3;            // staging token row 0..31
    int skk  = (tid & 7) * 8;       // staging k offset
    size_t srow = (size_t)tokid[stok] * H_DIM;

    union U8 { ushort v[8]; uint4 q; };
    auto load8 = [&](int k0) -> uint4 {
        U8 u;
        if (BF) {
            u.q = *(const uint4*)((const ushort*)x + srow + k0 + skk);
        } else {
            const float* xp = (const float*)x + srow + k0 + skk;
            #pragma unroll
            for (int j = 0; j < 8; ++j) u.v[j] = f2b(xp[j]);
        }
        return u.q;
    };

    f32x4 Cg[2][4], Cu[2][4];
    #pragma unroll
    for (int m = 0; m < 2; ++m)
        #pragma unroll
        for (int j = 0; j < 4; ++j) { Cg[m][j] = (f32x4)0.f; Cu[m][j] = (f32x4)0.f; }

    *(uint4*)&xA[0][stok * XS + skk] = load8(0);
    __syncthreads();

    const ushort* Bg_base = Wg_t + ((size_t)e * I_DIM + (w*64 + l15)) * H_DIM + q*8;
    const ushort* Bu_base = Wu_t + ((size_t)e * I_DIM + (w*64 + l15)) * H_DIM + q*8;

    for (int s = 0; s < 16; ++s) {
        int buf = s & 1;
        uint4 nxt;
        if (s < 15) nxt = load8((s + 1) * 64);
        #pragma unroll
        for (int kc = 0; kc < 2; ++kc) {
            int kk = kc * 32;
            bf16x8 A0 = *(bf16x8*)&xA[buf][(l15)      * XS + kk + q*8];
            bf16x8 A1 = *(bf16x8*)&xA[buf][(l15 + 16) * XS + kk + q*8];
            #pragma unroll
            for (int j = 0; j < 4; ++j) {
                bf16x8 Bg = *(const bf16x8*)(Bg_base + (size_t)j*16*H_DIM + s*64 + kk);
                bf16x8 Bu = *(const bf16x8*)(Bu_base + (size_t)j*16*H_DIM + s*64 + kk);
                Cg[0][j] = mfma_bf16(A0, Bg, Cg[0][j]);
                Cg[1][j] = mfma_bf16(A1, Bg, Cg[1][j]);
                Cu[0][j] = mfma_bf16(A0, Bu, Cu[0][j]);
                Cu[1][j] = mfma_bf16(A1, Bu, Cu[1][j]);
            }
        }
        if (s < 15) *(uint4*)&xA[buf ^ 1][stok * XS + skk] = nxt;
        __syncthreads();
    }

    // h = silu(g) * u -> LDS (bf16, K-contiguous rows for down-proj A-frags)
    #pragma unroll
    for (int m = 0; m < 2; ++m)
        #pragma unroll
        for (int j = 0; j < 4; ++j)
            #pragma unroll
            for (int r = 0; r < 4; ++r) {
                float g = Cg[m][j][r], u = Cu[m][j][r];
                float h = (g / (1.f + expf(-g))) * u;
                int tr  = m*16 + q*4 + r;
                int col = w*64 + j*16 + l15;
                hsm[tr * 264 + col] = f2b(h);
            }
    __syncthreads();

    // down projection
    f32x4 Cd[2][8];
    #pragma unroll
    for (int m = 0; m < 2; ++m)
        #pragma unroll
        for (int j = 0; j < 8; ++j) Cd[m][j] = (f32x4)0.f;

    const ushort* Bd_base = Wd_t + ((size_t)e * O_DIM + (w*128 + l15)) * I_DIM + q*8;
    #pragma unroll
    for (int kc = 0; kc < 8; ++kc) {
        int kk = kc * 32;
        bf16x8 A0 = *(bf16x8*)&hsm[(l15)      * 264 + kk + q*8];
        bf16x8 A1 = *(bf16x8*)&hsm[(l15 + 16) * 264 + kk + q*8];
        #pragma unroll
        for (int j = 0; j < 8; ++j) {
            bf16x8 Bd = *(const bf16x8*)(Bd_base + (size_t)j*16*I_DIM + kk);
            Cd[0][j] = mfma_bf16(A0, Bd, Cd[0][j]);
            Cd[1][j] = mfma_bf16(A1, Bd, Cd[1][j]);
        }
    }

    int gsel = e >> 4;
    size_t colbase = (size_t)gsel * O_DIM;
    #pragma unroll
    for (int m = 0; m < 2; ++m)
        #pragma unroll
        for (int r = 0; r < 4; ++r) {
            int mt = m*16 + q*4 + r;
            if (t0 + mt < n) {
                float ww = twt[mt];
                int   tk = tokid[mt];
                #pragma unroll
                for (int j = 0; j < 8; ++j)
                    atomicAdd(&z[(size_t)tk * H_DIM + colbase + w*128 + j*16 + l15],
                              ww * Cd[m][j][r]);
            }
        }
}

__global__ __launch_bounds__(256) void expert_mfma_kernel(
    const void* x, const ushort* Wg_t, const ushort* Wu_t, const ushort* Wd_t,
    const int* flag, const int* counts, const int* tok_list, const float* wt_list,
    float* z)
{
    if (*flag) expert_mfma_body<1>(x, Wg_t, Wu_t, Wd_t, counts, tok_list, wt_list, z);
    else       expert_mfma_body<0>(x, Wg_t, Wu_t, Wd_t, counts, tok_list, wt_list, z);
}

// ---------------------------------------------------------------------------
// MFMA Wc kernel: out[2048][1024] = z[2048][1024] @ Wc. Block = 32 rows x 256
// cols, grid (64,4). z staged fp32->bf16 double-buffered; B = Wc_t bf16.
// ---------------------------------------------------------------------------
template<int BF>
__device__ void wc_mfma_body(const float* __restrict__ z, const ushort* __restrict__ Wc_t,
                             void* __restrict__ out_base)
{
    int m0  = blockIdx.x * 32;
    int n0g = blockIdx.y * 256;
    int tid = threadIdx.x;
    int lane = tid & 63, w = tid >> 6;
    int q = lane >> 4, l15 = lane & 15;

    __shared__ ushort zA[2][32 * XS];

    int stok = tid >> 3;
    int skk  = (tid & 7) * 8;
    const float* zrow = z + (size_t)(m0 + stok) * H_DIM;

    union U8 { ushort v[8]; uint4 q; };
    auto load8 = [&](int k0) -> uint4 {
        U8 u;
        #pragma unroll
        for (int j = 0; j < 8; ++j) u.v[j] = f2b(zrow[k0 + skk + j]);
        return u.q;
    };

    f32x4 C[2][4];
    #pragma unroll
    for (int m = 0; m < 2; ++m)
        #pragma unroll
        for (int j = 0; j < 4; ++j) C[m][j] = (f32x4)0.f;

    *(uint4*)&zA[0][stok * XS + skk] = load8(0);
    __syncthreads();

    const ushort* Bc_base = Wc_t + ((size_t)(n0g + w*64 + l15)) * H_DIM + q*8;

    for (int s = 0; s < 16; ++s) {
        int buf = s & 1;
        uint4 nxt;
        if (s < 15) nxt = load8((s + 1) * 64);
        #pragma unroll
        for (int kc = 0; kc < 2; ++kc) {
            int kk = kc * 32;
            bf16x8 A0 = *(bf16x8*)&zA[buf][(l15)      * XS + kk + q*8];
            bf16x8 A1 = *(bf16x8*)&zA[buf][(l15 + 16) * XS + kk + q*8];
            #pragma unroll
            for (int j = 0; j < 4; ++j) {
                bf16x8 Bc = *(const bf16x8*)(Bc_base + (size_t)j*16*H_DIM + s*64 + kk);
                C[0][j] = mfma_bf16(A0, Bc, C[0][j]);
                C[1][j] = mfma_bf16(A1, Bc, C[1][j]);
            }
        }
        if (s < 15) *(uint4*)&zA[buf ^ 1][stok * XS + skk] = nxt;
        __syncthreads();
    }

    #pragma unroll
    for (int m = 0; m < 2; ++m)
        #pragma unroll
        for (int j = 0; j < 4; ++j)
            #pragma unroll
            for (int r = 0; r < 4; ++r) {
                int row = m0 + m*16 + q*4 + r;
                int col = n0g + w*64 + j*16 + l15;
                size_t o = (size_t)row * H_DIM + col;
                if (BF) ((hbf16*)out_base)[o] = __float2bfloat16(C[m][j][r]);
                else    ((float*)out_base)[o] = C[m][j][r];
            }
}

__global__ __launch_bounds__(256) void wc_mfma_kernel(
    const float* z, const ushort* Wc_t, void* out_base, const int* flag)
{
    if (*flag) wc_mfma_body<1>(z, Wc_t, out_base);
    else       wc_mfma_body<0>(z, Wc_t, out_base);
}

// ===========================================================================
// ===============  FALLBACK PATH (round-4, known passing)  ==================
// ===========================================================================

__global__ __launch_bounds__(256) void zero_kernel(
    float* __restrict__ z_fp32, float* __restrict__ z_bf16,
    const int* __restrict__ flag, int* __restrict__ counts)
{
    float* base = (*flag) ? z_bf16 : z_fp32;
    size_t i = (size_t)blockIdx.x * 256 + threadIdx.x;
    ((float4*)base)[i] = make_float4(0.f, 0.f, 0.f, 0.f);
    if (blockIdx.x == 0 && threadIdx.x < E_NUM) counts[threadIdx.x] = 0;
}

template<int BF>
__device__ void router_body(const void* __restrict__ x, const void* __restrict__ Wr,
                            void* __restrict__ out_base,
                            int* __restrict__ counts, int* __restrict__ tok_list,
                            float* __restrict__ wt_list)
{
    int t    = blockIdx.x;
    int lane = threadIdx.x;
    int e    = lane & 31;
    int half = lane >> 5;

    float acc = 0.f;
    size_t xoff = (size_t)t * H_DIM;
    int h0 = half * (H_DIM / 2);
    for (int h = h0; h < h0 + H_DIM / 2; ++h)
        acc = fmaf(ld<BF>(x, xoff + h), ld<BF>(Wr, (size_t)h * E_NUM + e), acc);
    acc += __shfl_down(acc, 32);

    __shared__ float sl[E_NUM];
    if (lane < 32) {
        sl[e] = acc;
        size_t li = (size_t)T_TOK * H_DIM + (size_t)t * E_NUM + e;
        if (BF) ((hbf16*)out_base)[li] = __float2bfloat16(acc);
        else    ((float*)out_base)[li] = acc;
    }
    __syncthreads();

    if (lane == 0) {
        float s[E_NUM];
        #pragma unroll
        for (int i = 0; i < E_NUM; ++i) s[i] = sl[i];

        int   selE[4];
        float selL[4];
        int ns = 0;
        for (int g = 0; g < 2; ++g) {
            float sum0 = 0.f, sum1 = 0.f;
            #pragma unroll
            for (int j = 0; j < 8; ++j) {
                sum0 += s[(2*g)   * 8 + j];
                sum1 += s[(2*g+1) * 8 + j];
            }
            int bestSh = (sum1 > sum0) ? (2*g+1) : (2*g);
            int base = bestSh * 8;
            int i1 = 0;
            for (int j = 1; j < 8; ++j) if (s[base+j] > s[base+i1]) i1 = j;
            int i2 = -1;
            for (int j = 0; j < 8; ++j) {
                if (j == i1) continue;
                if (i2 < 0 || s[base+j] > s[base+i2]) i2 = j;
            }
            selE[ns] = base + i1; selL[ns] = s[base+i1]; ++ns;
            selE[ns] = base + i2; selL[ns] = s[base+i2]; ++ns;
        }
        float m = fmaxf(fmaxf(selL[0], selL[1]), fmaxf(selL[2], selL[3]));
        float w[4];
        float sum = 0.f;
        for (int j = 0; j < 4; ++j) { w[j] = expf(selL[j] - m); sum += w[j]; }
        float inv = 1.f / sum;
        for (int j = 0; j < 4; ++j) {
            int ee = selE[j];
            int pos = atomicAdd(&counts[ee], 1);
            if (pos >= 0 && pos < CAP) {
                tok_list[ee * CAP + pos] = t;
                wt_list[ee * CAP + pos]  = w[j] * inv;
            }
        }
    }
}

__global__ __launch_bounds__(64) void router_kernel(
    const void* x, const void* Wr, void* out_base, const int* flag,
    int* counts, int* tok_list, float* wt_list)
{
    if (*flag) router_body<1>(x, Wr, out_base, counts, tok_list, wt_list);
    else       router_body<0>(x, Wr, out_base, counts, tok_list, wt_list);
}

template<int BF>
__device__ void expert_body(const void* __restrict__ x,
                            const void* __restrict__ Wg, const void* __restrict__ Wu,
                            const void* __restrict__ Wd,
                            const int* __restrict__ counts, const int* __restrict__ tok_list,
                            const float* __restrict__ wt_list,
                            float* __restrict__ z)
{
    int e = blockIdx.x;
    int n = counts[e];
    n = n < 0 ? 0 : (n > CAP ? CAP : n);
    int t0 = blockIdx.y * TT;
    if (t0 >= n) return;
    int tid = threadIdx.x;

    __shared__ __align__(16) float xs[TT][H_DIM];
    float (*hs)[I_DIM] = reinterpret_cast<float(*)[I_DIM]>(&xs[0][0]);

    const int*   tl = tok_list + e * CAP;
    const float* wl = wt_list  + e * CAP;

    for (int idx = tid; idx < TT * H_DIM; idx += 256) {
        int tt = idx >> 10;
        int h  = idx & (H_DIM - 1);
        int it = t0 + tt;
        int tkn = (it < n) ? tl[it] : tl[t0];
        tkn = (tkn < 0) ? 0 : (tkn >= T_TOK ? T_TOK - 1 : tkn);
        xs[tt][h] = ld<BF>(x, (size_t)tkn * H_DIM + h);
    }
    __syncthreads();

    size_t wbase = (size_t)e * H_DIM * I_DIM + tid;
    float ag[TT], au[TT];
    #pragma unroll
    for (int tt = 0; tt < TT; ++tt) { ag[tt] = 0.f; au[tt] = 0.f; }

    for (int k = 0; k < H_DIM; k += 4) {
        float g0 = ld<BF>(Wg, wbase + (size_t)(k+0) * I_DIM);
        float g1 = ld<BF>(Wg, wbase + (size_t)(k+1) * I_DIM);
        float g2 = ld<BF>(Wg, wbase + (size_t)(k+2) * I_DIM);
        float g3 = ld<BF>(Wg, wbase + (size_t)(k+3) * I_DIM);
        float u0 = ld<BF>(Wu, wbase + (size_t)(k+0) * I_DIM);
        float u1 = ld<BF>(Wu, wbase + (size_t)(k+1) * I_DIM);
        float u2 = ld<BF>(Wu, wbase + (size_t)(k+2) * I_DIM);
        float u3 = ld<BF>(Wu, wbase + (size_t)(k+3) * I_DIM);
        #pragma unroll
        for (int tt = 0; tt < TT; ++tt) {
            float4 xv = *(const float4*)&xs[tt][k];
            ag[tt] = fmaf(xv.w, g3, fmaf(xv.z, g2, fmaf(xv.y, g1, fmaf(xv.x, g0, ag[tt]))));
            au[tt] = fmaf(xv.w, u3, fmaf(xv.z, u2, fmaf(xv.y, u1, fmaf(xv.x, u0, au[tt]))));
        }
    }
    float hval[TT];
    #pragma unroll
    for (int tt = 0; tt < TT; ++tt) {
        float g = ag[tt];
        hval[tt] = (g / (1.f + expf(-g))) * au[tt];
    }
    __syncthreads();
    #pragma unroll
    for (int tt = 0; tt < TT; ++tt) hs[tt][tid] = hval[tt];
    __syncthreads();

    size_t dbase = (size_t)e * I_DIM * O_DIM;
    float y0[TT], y1[TT];
    #pragma unroll
    for (int tt = 0; tt < TT; ++tt) { y0[tt] = 0.f; y1[tt] = 0.f; }

    for (int k = 0; k < I_DIM; k += 4) {
        float d00 = ld<BF>(Wd, dbase + (size_t)(k+0) * O_DIM + tid);
        float d01 = ld<BF>(Wd, dbase + (size_t)(k+1) * O_DIM + tid);
        float d02 = ld<BF>(Wd, dbase + (size_t)(k+2) * O_DIM + tid);
        float d03 = ld<BF>(Wd, dbase + (size_t)(k+3) * O_DIM + tid);
        float d10 = ld<BF>(Wd, dbase + (size_t)(k+0) * O_DIM + tid + 256);
        float d11 = ld<BF>(Wd, dbase + (size_t)(k+1) * O_DIM + tid + 256);
        float d12 = ld<BF>(Wd, dbase + (size_t)(k+2) * O_DIM + tid + 256);
        float d13 = ld<BF>(Wd, dbase + (size_t)(k+3) * O_DIM + tid + 256);
        #pragma unroll
        for (int tt = 0; tt < TT; ++tt) {
            float4 hv = *(const float4*)&hs[tt][k];
            y0[tt] = fmaf(hv.w, d03, fmaf(hv.z, d02, fmaf(hv.y, d01, fmaf(hv.x, d00, y0[tt]))));
            y1[tt] = fmaf(hv.w, d13, fmaf(hv.z, d12, fmaf(hv.y, d11, fmaf(hv.x, d10, y1[tt]))));
        }
    }

    int gsel = e >> 4;
    size_t colbase = (size_t)gsel * O_DIM;
    #pragma unroll
    for (int tt = 0; tt < TT; ++tt) {
        int it = t0 + tt;
        if (it < n) {
            float w  = wl[it];
            int tkn = tl[it];
            tkn = (tkn < 0) ? 0 : (tkn >= T_TOK ? T_TOK - 1 : tkn);
            atomicAdd(&z[(size_t)tkn * H_DIM + colbase + tid],       w * y0[tt]);
            atomicAdd(&z[(size_t)tkn * H_DIM + colbase + tid + 256], w * y1[tt]);
        }
    }
}

__global__ __launch_bounds__(256) void expert_kernel(
    const void* x, const void* Wg, const void* Wu, const void* Wd,
    const int* flag, const int* counts, const int* tok_list, const float* wt_list,
    float* z_fp32, float* z_bf16)
{
    if (*flag) expert_body<1>(x, Wg, Wu, Wd, counts, tok_list, wt_list, z_bf16);
    else       expert_body<0>(x, Wg, Wu, Wd, counts, tok_list, wt_list, z_fp32);
}

template<int BF>
__device__ void wc_body(const float* __restrict__ z, const void* __restrict__ Wc,
                        void* __restrict__ out_base)
{
    int t0  = blockIdx.x * WT;
    int tid = threadIdx.x;

    __shared__ __align__(16) float ps[WT][H_DIM];
    for (int idx = tid; idx < WT * H_DIM; idx += 256) {
        int tt = idx >> 10;
        int h  = idx & (H_DIM - 1);
        ps[tt][h] = z[(size_t)(t0 + tt) * H_DIM + h];
    }
    __syncthreads();

    float acc[WT][4];
    #pragma unroll
    for (int tt = 0; tt < WT; ++tt)
        #pragma unroll
        for (int q = 0; q < 4; ++q) acc[tt][q] = 0.f;

    for (int k = 0; k < H_DIM; k += 2) {
        float c00 = ld<BF>(Wc, (size_t)(k+0) * H_DIM + tid);
        float c01 = ld<BF>(Wc, (size_t)(k+0) * H_DIM + tid + 256);
        float c02 = ld<BF>(Wc, (size_t)(k+0) * H_DIM + tid + 512);
        float c03 = ld<BF>(Wc, (size_t)(k+0) * H_DIM + tid + 768);
        float c10 = ld<BF>(Wc, (size_t)(k+1) * H_DIM + tid);
        float c11 = ld<BF>(Wc, (size_t)(k+1) * H_DIM + tid + 256);
        float c12 = ld<BF>(Wc, (size_t)(k+1) * H_DIM + tid + 512);
        float c13 = ld<BF>(Wc, (size_t)(k+1) * H_DIM + tid + 768);
        #pragma unroll
        for (int tt = 0; tt < WT; ++tt) {
            float2 pv = *(const float2*)&ps[tt][k];
            acc[tt][0] = fmaf(pv.y, c10, fmaf(pv.x, c00, acc[tt][0]));
            acc[tt][1] = fmaf(pv.y, c11, fmaf(pv.x, c01, acc[tt][1]));
            acc[tt][2] = fmaf(pv.y, c12, fmaf(pv.x, c02, acc[tt][2]));
            acc[tt][3] = fmaf(pv.y, c13, fmaf(pv.x, c03, acc[tt][3]));
        }
    }

    #pragma unroll
    for (int tt = 0; tt < WT; ++tt) {
        #pragma unroll
        for (int q = 0; q < 4; ++q) {
            size_t o = (size_t)(t0 + tt) * H_DIM + tid + 256 * q;
            if (BF) ((hbf16*)out_base)[o] = __float2bfloat16(acc[tt][q]);
            else    ((float*)out_base)[o] = acc[tt][q];
        }
    }
}

__global__ __launch_bounds__(256) void wc_kernel(
    const float* z_fp32, const float* z_bf16, const void* Wc,
    void* out_base, const int* flag)
{
    if (*flag) wc_body<1>(z_bf16, Wc, out_base);
    else       wc_body<0>(z_fp32, Wc, out_base);
}

// ---------------------------------------------------------------------------
extern "C" void kernel_launch(void* const* d_in, const int* in_sizes, int n_in,
                              void* d_out, int out_size, void* d_ws, size_t ws_size,
                              hipStream_t stream)
{
    (void)in_sizes; (void)n_in; (void)out_size;

    const void* x  = d_in[0];
    const void* Wr = d_in[1];
    const void* Wg = d_in[2];
    const void* Wu = d_in[3];
    const void* Wd = d_in[4];
    const void* Wc = d_in[5];

    char* ws = (char*)d_ws;
    int*   counts   = (int*)(ws + 0);
    int*   flag     = (int*)(ws + 128);
    int*   tok_list = (int*)(ws + 4096);
    float* wt_list  = (float*)(ws + 4096 + (size_t)E_NUM * CAP * 4);

    detect_kernel<<<1, 64, 0, stream>>>((const uint32_t*)x, flag);

    if (ws_size >= ((size_t)58 << 20)) {
        // ---------------- fast MFMA path ----------------
        float*  z    = (float*)(ws + ((size_t)1  << 20));   // 8 MB fp32
        ushort* Wg_t = (ushort*)(ws + ((size_t)16 << 20));  // 16 MB
        ushort* Wu_t = (ushort*)(ws + ((size_t)32 << 20));  // 16 MB
        ushort* Wd_t = (ushort*)(ws + ((size_t)48 << 20));  // 8 MB
        ushort* Wc_t = (ushort*)(ws + ((size_t)56 << 20));  // 2 MB

        zero_fast_kernel<<<2048, 256, 0, stream>>>(z, counts);
        convert_t_kernel<<<32*32*8,  256, 0, stream>>>(Wg, Wg_t, flag, 1024, 256);
        convert_t_kernel<<<32*32*8,  256, 0, stream>>>(Wu, Wu_t, flag, 1024, 256);
        convert_t_kernel<<<32*8*16,  256, 0, stream>>>(Wd, Wd_t, flag, 256, 512);
        convert_t_kernel<<<32*32,    256, 0, stream>>>(Wc, Wc_t, flag, 1024, 1024);
        router_fast_kernel<<<T_TOK/8, 256, 0, stream>>>(x, Wr, d_out, flag,
                                                        counts, tok_list, wt_list);
        expert_mfma_kernel<<<dim3(E_NUM, 64), 256, 0, stream>>>(
            x, Wg_t, Wu_t, Wd_t, flag, counts, tok_list, wt_list, z);
        wc_mfma_kernel<<<dim3(64, 4), 256, 0, stream>>>(z, Wc_t, d_out, flag);
    } else {
        // ---------------- round-4 fallback ----------------
        float* z_bf16 = (float*)(ws + (1u << 20));
        float* z_fp32 = (float*)d_out;
        zero_kernel<<<T_TOK, 256, 0, stream>>>(z_fp32, z_bf16, flag, counts);
        router_kernel<<<T_TOK, 64, 0, stream>>>(x, Wr, d_out, flag, counts, tok_list, wt_list);
        expert_kernel<<<dim3(E_NUM, T_TOK / TT), 256, 0, stream>>>(
            x, Wg, Wu, Wd, flag, counts, tok_list, wt_list, z_fp32, z_bf16);
        wc_kernel<<<T_TOK / WT, 256, 0, stream>>>(z_fp32, z_bf16, Wc, d_out, flag);
    }
}

// Round 6
// 306.536 us; speedup vs baseline: 3.9764x; 1.1997x over previous
//
#include <hip/hip_runtime.h>
#include <hip/hip_bf16.h>
#include <math.h>
#include <stdint.h>

typedef __hip_bfloat16 hbf16;

#define T_TOK 2048
#define H_DIM 1024
#define E_NUM 32
#define I_DIM 256
#define O_DIM 512
#define CAP   2048
#define TT    16
#define WT    16
#define MT    64    // expert tile tokens (M)
#define XS    72    // xA row stride (ushort): 144B row, 16B-aligned, 2-way banks
#define HS    280   // hsm row stride (ushort): 560B row, 16B-aligned, 2-way banks

typedef __bf16 bf16x8 __attribute__((ext_vector_type(8)));
typedef float  f32x4  __attribute__((ext_vector_type(4)));

__device__ __forceinline__ float b2f(hbf16 v) { return __bfloat162float(v); }

__device__ __forceinline__ ushort f2b(float f) {   // fp32->bf16 RNE
    uint32_t u = __float_as_uint(f);
    return (ushort)((u + 0x7FFFu + ((u >> 16) & 1u)) >> 16);
}

template<int BF>
__device__ __forceinline__ float ld(const void* p, size_t i) {
    if (BF) return b2f(((const hbf16*)p)[i]);
    else    return ((const float*)p)[i];
}

__device__ __forceinline__ f32x4 mfma_bf16(bf16x8 a, bf16x8 b, f32x4 c) {
    return __builtin_amdgcn_mfma_f32_16x16x32_bf16(a, b, c, 0, 0, 0);
}

// ---------------------------------------------------------------------------
// detect: 256 threads, 4 words each, LDS reduce.
// ---------------------------------------------------------------------------
__global__ __launch_bounds__(256) void detect_kernel(
    const uint32_t* __restrict__ xw, int* __restrict__ flag)
{
    __shared__ int cnt;
    if (threadIdx.x == 0) cnt = 0;
    __syncthreads();
    int c = 0;
    for (int i = threadIdx.x; i < 1024; i += 256) {
        int e = (xw[i] >> 7) & 0xFF;
        if (e >= 110 && e <= 140) c++;
    }
    atomicAdd(&cnt, c);
    __syncthreads();
    if (threadIdx.x == 0) *flag = (cnt > 512) ? 1 : 0;
}

// ===========================================================================
// FAST PATH (ws_size >= 58 MB)
// ===========================================================================

__global__ __launch_bounds__(256) void zero_fast_kernel(
    float* __restrict__ z, int* __restrict__ counts)
{
    size_t i = (size_t)blockIdx.x * 256 + threadIdx.x;
    ((float4*)z)[i] = make_float4(0.f, 0.f, 0.f, 0.f);
    if (blockIdx.x == 0 && threadIdx.x < E_NUM) counts[threadIdx.x] = 0;
}

// one fused transpose+convert kernel for all 4 weights
__device__ void conv_tile(const void* __restrict__ src, ushort* __restrict__ dst,
                          int bf, int K, int N, int b)
{
    int tilesN = N >> 5, tilesK = K >> 5;
    int e  = b / (tilesK * tilesN);
    int r  = b % (tilesK * tilesN);
    int k0 = (r / tilesN) << 5;
    int n0 = (r % tilesN) << 5;
    size_t base = (size_t)e * K * N;
    __shared__ float sh[32][33];
    int tid = threadIdx.x;
    #pragma unroll
    for (int it = 0; it < 4; ++it) {
        int idx = tid + it * 256;
        int rr = idx >> 5, cc = idx & 31;
        size_t si = base + (size_t)(k0 + rr) * N + n0 + cc;
        sh[rr][cc] = bf ? b2f(((const hbf16*)src)[si]) : ((const float*)src)[si];
    }
    __syncthreads();
    #pragma unroll
    for (int it = 0; it < 4; ++it) {
        int idx = tid + it * 256;
        int rr = idx >> 5, cc = idx & 31;
        dst[base + (size_t)(n0 + rr) * K + k0 + cc] = f2b(sh[cc][rr]);
    }
}

__global__ __launch_bounds__(256) void convert_all_kernel(
    const void* Wg, const void* Wu, const void* Wd, const void* Wc,
    ushort* Wg_t, ushort* Wu_t, ushort* Wd_t, ushort* Wc_t,
    const int* __restrict__ flag)
{
    int bf = *flag;
    int b = blockIdx.x;
    if      (b < 8192)  conv_tile(Wg, Wg_t, bf, 1024,  256, b);
    else if (b < 16384) conv_tile(Wu, Wu_t, bf, 1024,  256, b - 8192);
    else if (b < 20480) conv_tile(Wd, Wd_t, bf,  256,  512, b - 16384);
    else                conv_tile(Wc, Wc_t, bf, 1024, 1024, b - 20480);
}

// ---------------------------------------------------------------------------
// router2: 8 tokens/block, 256 blocks. LDS-tiled fp32 GEMM + selection.
// ---------------------------------------------------------------------------
template<int BF>
__device__ void router2_body(const void* __restrict__ x, const void* __restrict__ Wr,
                             void* __restrict__ out_base,
                             int* __restrict__ counts, int* __restrict__ tok_list,
                             float* __restrict__ wt_list)
{
    __shared__ float xs[8][128];     // 4 KB
    __shared__ float wrs[128 * 32];  // 16 KB
    __shared__ float sl[8][32];      // 1 KB
    int tid = threadIdx.x;
    int t0  = blockIdx.x * 8;
    int e   = tid & 31;
    int ta  = tid >> 5;              // 0..7

    float acc = 0.f;
    for (int k0 = 0; k0 < H_DIM; k0 += 128) {
        __syncthreads();
        // stage x chunk: 8 tok x 128 k (256 float4)
        {
            int i = tid;                      // one f4 per thread
            int tr = i >> 5, c = (i & 31) * 4;
            if (!BF) {
                *(float4*)&xs[tr][c] = *(const float4*)((const float*)x +
                                         (size_t)(t0 + tr) * H_DIM + k0 + c);
            } else {
                const hbf16* xp = (const hbf16*)x + (size_t)(t0 + tr) * H_DIM + k0 + c;
                xs[tr][c+0] = b2f(xp[0]); xs[tr][c+1] = b2f(xp[1]);
                xs[tr][c+2] = b2f(xp[2]); xs[tr][c+3] = b2f(xp[3]);
            }
        }
        // stage Wr chunk: contiguous 128x32 floats (1024 float4)
        for (int i = tid; i < 1024; i += 256) {
            if (!BF) {
                ((float4*)wrs)[i] = *((const float4*)((const float*)Wr + (size_t)k0 * 32) + i);
            } else {
                const hbf16* wp = (const hbf16*)Wr + (size_t)k0 * 32 + i * 4;
                wrs[i*4+0] = b2f(wp[0]); wrs[i*4+1] = b2f(wp[1]);
                wrs[i*4+2] = b2f(wp[2]); wrs[i*4+3] = b2f(wp[3]);
            }
        }
        __syncthreads();
        #pragma unroll 8
        for (int k = 0; k < 128; k += 4) {
            float4 xv = *(const float4*)&xs[ta][k];
            float w0 = wrs[(k+0)*32 + e];
            float w1 = wrs[(k+1)*32 + e];
            float w2 = wrs[(k+2)*32 + e];
            float w3 = wrs[(k+3)*32 + e];
            acc = fmaf(xv.w, w3, fmaf(xv.z, w2, fmaf(xv.y, w1, fmaf(xv.x, w0, acc))));
        }
    }
    sl[ta][e] = acc;
    size_t li = (size_t)T_TOK * H_DIM + (size_t)(t0 + ta) * E_NUM + e;
    if (BF) ((hbf16*)out_base)[li] = __float2bfloat16(acc);
    else    ((float*)out_base)[li] = acc;
    __syncthreads();

    if (tid < 8) {
        int t = t0 + tid;
        float s[E_NUM];
        #pragma unroll
        for (int i = 0; i < E_NUM; ++i) s[i] = sl[tid][i];

        int   selE[4];
        float selL[4];
        int ns = 0;
        for (int g = 0; g < 2; ++g) {
            float sum0 = 0.f, sum1 = 0.f;
            #pragma unroll
            for (int j = 0; j < 8; ++j) {
                sum0 += s[(2*g)   * 8 + j];
                sum1 += s[(2*g+1) * 8 + j];
            }
            int bestSh = (sum1 > sum0) ? (2*g+1) : (2*g);
            int base = bestSh * 8;
            int i1 = 0;
            for (int j = 1; j < 8; ++j) if (s[base+j] > s[base+i1]) i1 = j;
            int i2 = -1;
            for (int j = 0; j < 8; ++j) {
                if (j == i1) continue;
                if (i2 < 0 || s[base+j] > s[base+i2]) i2 = j;
            }
            selE[ns] = base + i1; selL[ns] = s[base+i1]; ++ns;
            selE[ns] = base + i2; selL[ns] = s[base+i2]; ++ns;
        }
        float m = fmaxf(fmaxf(selL[0], selL[1]), fmaxf(selL[2], selL[3]));
        float w[4];
        float sum = 0.f;
        for (int j = 0; j < 4; ++j) { w[j] = expf(selL[j] - m); sum += w[j]; }
        float inv = 1.f / sum;
        for (int j = 0; j < 4; ++j) {
            int ee = selE[j];
            int pos = atomicAdd(&counts[ee], 1);
            if (pos >= 0 && pos < CAP) {
                tok_list[ee * CAP + pos] = t;
                wt_list[ee * CAP + pos]  = w[j] * inv;
            }
        }
    }
}

__global__ __launch_bounds__(256) void router2_kernel(
    const void* x, const void* Wr, void* out_base, const int* flag,
    int* counts, int* tok_list, float* wt_list)
{
    if (*flag) router2_body<1>(x, Wr, out_base, counts, tok_list, wt_list);
    else       router2_body<0>(x, Wr, out_base, counts, tok_list, wt_list);
}

// ---------------------------------------------------------------------------
// expert2: M=64 tokens/block, 4 waves. gate/up N=256 (64 cols/wave),
// down N=512 (128 cols/wave). bf16 MFMA, fp32 acc, atomic combine into z.
// ---------------------------------------------------------------------------
template<int BF>
__device__ void expert2_body(const void* __restrict__ x,
    const ushort* __restrict__ Wg_t, const ushort* __restrict__ Wu_t,
    const ushort* __restrict__ Wd_t,
    const int* __restrict__ counts, const int* __restrict__ tok_list,
    const float* __restrict__ wt_list, float* __restrict__ z)
{
    int e = blockIdx.x;
    int n = counts[e]; n = n < 0 ? 0 : (n > CAP ? CAP : n);
    int t0 = blockIdx.y * MT;
    if (t0 >= n) return;
    int tid  = threadIdx.x;
    int lane = tid & 63, wv = tid >> 6;
    int q = lane >> 4, l15 = lane & 15;

    __shared__ ushort xA[2][MT * XS];   // 18.4 KB
    __shared__ ushort hsm[MT * HS];     // 35.8 KB
    __shared__ int    tokid[MT];
    __shared__ float  twt[MT];

    if (tid < MT) {
        int it = t0 + tid;
        int tk; float ww;
        if (it < n) { tk = tok_list[e*CAP + it]; ww = wt_list[e*CAP + it]; }
        else        { tk = tok_list[e*CAP + t0]; ww = 0.f; }
        tk = tk < 0 ? 0 : (tk >= T_TOK ? T_TOK - 1 : tk);
        tokid[tid] = tk; twt[tid] = ww;
    }
    __syncthreads();

    int r0  = tid >> 3;          // 0..31; thread stages rows r0 and r0+32
    int skk = (tid & 7) * 8;
    size_t srow0 = (size_t)tokid[r0]      * H_DIM;
    size_t srow1 = (size_t)tokid[r0 + 32] * H_DIM;

    union U8 { ushort v[8]; uint4 q; };
    auto load8 = [&](size_t srow, int k0) -> uint4 {
        U8 u;
        if (BF) {
            u.q = *(const uint4*)((const ushort*)x + srow + k0 + skk);
        } else {
            const float* xp = (const float*)x + srow + k0 + skk;
            #pragma unroll
            for (int j = 0; j < 8; ++j) u.v[j] = f2b(xp[j]);
        }
        return u.q;
    };

    f32x4 Cg[4][4], Cu[4][4];
    #pragma unroll
    for (int m = 0; m < 4; ++m)
        #pragma unroll
        for (int j = 0; j < 4; ++j) { Cg[m][j] = (f32x4)0.f; Cu[m][j] = (f32x4)0.f; }

    *(uint4*)&xA[0][r0 * XS + skk]        = load8(srow0, 0);
    *(uint4*)&xA[0][(r0 + 32) * XS + skk] = load8(srow1, 0);
    __syncthreads();

    const ushort* Bg_base = Wg_t + ((size_t)e * I_DIM + wv*64 + l15) * H_DIM + q*8;
    const ushort* Bu_base = Wu_t + ((size_t)e * I_DIM + wv*64 + l15) * H_DIM + q*8;

    for (int s = 0; s < 16; ++s) {
        int buf = s & 1;
        uint4 nx0, nx1;
        if (s < 15) { nx0 = load8(srow0, (s+1)*64); nx1 = load8(srow1, (s+1)*64); }
        #pragma unroll
        for (int kc = 0; kc < 2; ++kc) {
            int kk = kc * 32;
            bf16x8 A[4];
            #pragma unroll
            for (int m = 0; m < 4; ++m)
                A[m] = *(bf16x8*)&xA[buf][(m*16 + l15) * XS + kk + q*8];
            #pragma unroll
            for (int j = 0; j < 4; ++j) {
                bf16x8 Bg = *(const bf16x8*)(Bg_base + (size_t)j*16*H_DIM + s*64 + kk);
                bf16x8 Bu = *(const bf16x8*)(Bu_base + (size_t)j*16*H_DIM + s*64 + kk);
                #pragma unroll
                for (int m = 0; m < 4; ++m) {
                    Cg[m][j] = mfma_bf16(A[m], Bg, Cg[m][j]);
                    Cu[m][j] = mfma_bf16(A[m], Bu, Cu[m][j]);
                }
            }
        }
        if (s < 15) {
            *(uint4*)&xA[buf ^ 1][r0 * XS + skk]        = nx0;
            *(uint4*)&xA[buf ^ 1][(r0 + 32) * XS + skk] = nx1;
        }
        __syncthreads();
    }

    // h = silu(g)*u -> hsm (bf16, K-contiguous rows)
    #pragma unroll
    for (int m = 0; m < 4; ++m)
        #pragma unroll
        for (int j = 0; j < 4; ++j)
            #pragma unroll
            for (int r = 0; r < 4; ++r) {
                float g = Cg[m][j][r], u = Cu[m][j][r];
                float h = (g / (1.f + expf(-g))) * u;
                hsm[(m*16 + q*4 + r) * HS + wv*64 + j*16 + l15] = f2b(h);
            }
    __syncthreads();

    // down projection
    f32x4 Cd[4][8];
    #pragma unroll
    for (int m = 0; m < 4; ++m)
        #pragma unroll
        for (int j = 0; j < 8; ++j) Cd[m][j] = (f32x4)0.f;

    const ushort* Bd_base = Wd_t + ((size_t)e * O_DIM + wv*128 + l15) * I_DIM + q*8;
    #pragma unroll
    for (int kc = 0; kc < 8; ++kc) {
        int kk = kc * 32;
        bf16x8 A[4];
        #pragma unroll
        for (int m = 0; m < 4; ++m)
            A[m] = *(bf16x8*)&hsm[(m*16 + l15) * HS + kk + q*8];
        #pragma unroll
        for (int j = 0; j < 8; ++j) {
            bf16x8 Bd = *(const bf16x8*)(Bd_base + (size_t)j*16*I_DIM + kk);
            #pragma unroll
            for (int m = 0; m < 4; ++m)
                Cd[m][j] = mfma_bf16(A[m], Bd, Cd[m][j]);
        }
    }

    int gsel = e >> 4;
    size_t colbase = (size_t)gsel * O_DIM;
    #pragma unroll
    for (int m = 0; m < 4; ++m)
        #pragma unroll
        for (int r = 0; r < 4; ++r) {
            int row = m*16 + q*4 + r;
            if (t0 + row < n) {
                float ww = twt[row];
                int   tk = tokid[row];
                #pragma unroll
                for (int j = 0; j < 8; ++j)
                    atomicAdd(&z[(size_t)tk * H_DIM + colbase + wv*128 + j*16 + l15],
                              ww * Cd[m][j][r]);
            }
        }
}

__global__ __launch_bounds__(256) void expert2_kernel(
    const void* x, const ushort* Wg_t, const ushort* Wu_t, const ushort* Wd_t,
    const int* flag, const int* counts, const int* tok_list, const float* wt_list,
    float* z)
{
    if (*flag) expert2_body<1>(x, Wg_t, Wu_t, Wd_t, counts, tok_list, wt_list, z);
    else       expert2_body<0>(x, Wg_t, Wu_t, Wd_t, counts, tok_list, wt_list, z);
}

// ---------------------------------------------------------------------------
// wc2: out = z @ Wc. M=64 rows x N=256 cols per block, grid (32,4).
// ---------------------------------------------------------------------------
template<int BF>
__device__ void wc2_body(const float* __restrict__ z, const ushort* __restrict__ Wc_t,
                         void* __restrict__ out_base)
{
    int m0  = blockIdx.x * MT;
    int n0  = blockIdx.y * 256;
    int tid = threadIdx.x;
    int lane = tid & 63, wv = tid >> 6;
    int q = lane >> 4, l15 = lane & 15;

    __shared__ ushort zA[2][MT * XS];

    int r0  = tid >> 3;
    int skk = (tid & 7) * 8;
    const float* zr0 = z + (size_t)(m0 + r0)      * H_DIM + skk;
    const float* zr1 = z + (size_t)(m0 + r0 + 32) * H_DIM + skk;

    union U8 { ushort v[8]; uint4 q; };
    auto load8 = [&](const float* zr, int k0) -> uint4 {
        U8 u;
        #pragma unroll
        for (int j = 0; j < 8; ++j) u.v[j] = f2b(zr[k0 + j]);
        return u.q;
    };

    f32x4 C[4][4];
    #pragma unroll
    for (int m = 0; m < 4; ++m)
        #pragma unroll
        for (int j = 0; j < 4; ++j) C[m][j] = (f32x4)0.f;

    *(uint4*)&zA[0][r0 * XS + skk]        = load8(zr0, 0);
    *(uint4*)&zA[0][(r0 + 32) * XS + skk] = load8(zr1, 0);
    __syncthreads();

    const ushort* Bc_base = Wc_t + ((size_t)(n0 + wv*64 + l15)) * H_DIM + q*8;

    for (int s = 0; s < 16; ++s) {
        int buf = s & 1;
        uint4 nx0, nx1;
        if (s < 15) { nx0 = load8(zr0, (s+1)*64); nx1 = load8(zr1, (s+1)*64); }
        #pragma unroll
        for (int kc = 0; kc < 2; ++kc) {
            int kk = kc * 32;
            bf16x8 A[4];
            #pragma unroll
            for (int m = 0; m < 4; ++m)
                A[m] = *(bf16x8*)&zA[buf][(m*16 + l15) * XS + kk + q*8];
            #pragma unroll
            for (int j = 0; j < 4; ++j) {
                bf16x8 Bc = *(const bf16x8*)(Bc_base + (size_t)j*16*H_DIM + s*64 + kk);
                #pragma unroll
                for (int m = 0; m < 4; ++m)
                    C[m][j] = mfma_bf16(A[m], Bc, C[m][j]);
            }
        }
        if (s < 15) {
            *(uint4*)&zA[buf ^ 1][r0 * XS + skk]        = nx0;
            *(uint4*)&zA[buf ^ 1][(r0 + 32) * XS + skk] = nx1;
        }
        __syncthreads();
    }

    #pragma unroll
    for (int m = 0; m < 4; ++m)
        #pragma unroll
        for (int j = 0; j < 4; ++j)
            #pragma unroll
            for (int r = 0; r < 4; ++r) {
                int row = m0 + m*16 + q*4 + r;
                int col = n0 + wv*64 + j*16 + l15;
                size_t o = (size_t)row * H_DIM + col;
                if (BF) ((hbf16*)out_base)[o] = __float2bfloat16(C[m][j][r]);
                else    ((float*)out_base)[o] = C[m][j][r];
            }
}

__global__ __launch_bounds__(256) void wc2_kernel(
    const float* z, const ushort* Wc_t, void* out_base, const int* flag)
{
    if (*flag) wc2_body<1>(z, Wc_t, out_base);
    else       wc2_body<0>(z, Wc_t, out_base);
}

// ===========================================================================
// FALLBACK PATH (round-4, known passing) — used only if ws is small
// ===========================================================================

__global__ __launch_bounds__(256) void zero_kernel(
    float* __restrict__ z_fp32, float* __restrict__ z_bf16,
    const int* __restrict__ flag, int* __restrict__ counts)
{
    float* base = (*flag) ? z_bf16 : z_fp32;
    size_t i = (size_t)blockIdx.x * 256 + threadIdx.x;
    ((float4*)base)[i] = make_float4(0.f, 0.f, 0.f, 0.f);
    if (blockIdx.x == 0 && threadIdx.x < E_NUM) counts[threadIdx.x] = 0;
}

template<int BF>
__device__ void router_body(const void* __restrict__ x, const void* __restrict__ Wr,
                            void* __restrict__ out_base,
                            int* __restrict__ counts, int* __restrict__ tok_list,
                            float* __restrict__ wt_list)
{
    int t    = blockIdx.x;
    int lane = threadIdx.x;
    int e    = lane & 31;
    int half = lane >> 5;

    float acc = 0.f;
    size_t xoff = (size_t)t * H_DIM;
    int h0 = half * (H_DIM / 2);
    for (int h = h0; h < h0 + H_DIM / 2; ++h)
        acc = fmaf(ld<BF>(x, xoff + h), ld<BF>(Wr, (size_t)h * E_NUM + e), acc);
    acc += __shfl_down(acc, 32);

    __shared__ float sl[E_NUM];
    if (lane < 32) {
        sl[e] = acc;
        size_t li = (size_t)T_TOK * H_DIM + (size_t)t * E_NUM + e;
        if (BF) ((hbf16*)out_base)[li] = __float2bfloat16(acc);
        else    ((float*)out_base)[li] = acc;
    }
    __syncthreads();

    if (lane == 0) {
        float s[E_NUM];
        #pragma unroll
        for (int i = 0; i < E_NUM; ++i) s[i] = sl[i];
        int   selE[4];
        float selL[4];
        int ns = 0;
        for (int g = 0; g < 2; ++g) {
            float sum0 = 0.f, sum1 = 0.f;
            #pragma unroll
            for (int j = 0; j < 8; ++j) {
                sum0 += s[(2*g)   * 8 + j];
                sum1 += s[(2*g+1) * 8 + j];
            }
            int bestSh = (sum1 > sum0) ? (2*g+1) : (2*g);
            int base = bestSh * 8;
            int i1 = 0;
            for (int j = 1; j < 8; ++j) if (s[base+j] > s[base+i1]) i1 = j;
            int i2 = -1;
            for (int j = 0; j < 8; ++j) {
                if (j == i1) continue;
                if (i2 < 0 || s[base+j] > s[base+i2]) i2 = j;
            }
            selE[ns] = base + i1; selL[ns] = s[base+i1]; ++ns;
            selE[ns] = base + i2; selL[ns] = s[base+i2]; ++ns;
        }
        float m = fmaxf(fmaxf(selL[0], selL[1]), fmaxf(selL[2], selL[3]));
        float w[4];
        float sum = 0.f;
        for (int j = 0; j < 4; ++j) { w[j] = expf(selL[j] - m); sum += w[j]; }
        float inv = 1.f / sum;
        for (int j = 0; j < 4; ++j) {
            int ee = selE[j];
            int pos = atomicAdd(&counts[ee], 1);
            if (pos >= 0 && pos < CAP) {
                tok_list[ee * CAP + pos] = t;
                wt_list[ee * CAP + pos]  = w[j] * inv;
            }
        }
    }
}

__global__ __launch_bounds__(64) void router_kernel(
    const void* x, const void* Wr, void* out_base, const int* flag,
    int* counts, int* tok_list, float* wt_list)
{
    if (*flag) router_body<1>(x, Wr, out_base, counts, tok_list, wt_list);
    else       router_body<0>(x, Wr, out_base, counts, tok_list, wt_list);
}

template<int BF>
__device__ void expert_body(const void* __restrict__ x,
                            const void* __restrict__ Wg, const void* __restrict__ Wu,
                            const void* __restrict__ Wd,
                            const int* __restrict__ counts, const int* __restrict__ tok_list,
                            const float* __restrict__ wt_list,
                            float* __restrict__ z)
{
    int e = blockIdx.x;
    int n = counts[e];
    n = n < 0 ? 0 : (n > CAP ? CAP : n);
    int t0 = blockIdx.y * TT;
    if (t0 >= n) return;
    int tid = threadIdx.x;

    __shared__ __align__(16) float xs[TT][H_DIM];
    float (*hs)[I_DIM] = reinterpret_cast<float(*)[I_DIM]>(&xs[0][0]);

    const int*   tl = tok_list + e * CAP;
    const float* wl = wt_list  + e * CAP;

    for (int idx = tid; idx < TT * H_DIM; idx += 256) {
        int tt = idx >> 10;
        int h  = idx & (H_DIM - 1);
        int it = t0 + tt;
        int tkn = (it < n) ? tl[it] : tl[t0];
        tkn = (tkn < 0) ? 0 : (tkn >= T_TOK ? T_TOK - 1 : tkn);
        xs[tt][h] = ld<BF>(x, (size_t)tkn * H_DIM + h);
    }
    __syncthreads();

    size_t wbase = (size_t)e * H_DIM * I_DIM + tid;
    float ag[TT], au[TT];
    #pragma unroll
    for (int tt = 0; tt < TT; ++tt) { ag[tt] = 0.f; au[tt] = 0.f; }

    for (int k = 0; k < H_DIM; k += 4) {
        float g0 = ld<BF>(Wg, wbase + (size_t)(k+0) * I_DIM);
        float g1 = ld<BF>(Wg, wbase + (size_t)(k+1) * I_DIM);
        float g2 = ld<BF>(Wg, wbase + (size_t)(k+2) * I_DIM);
        float g3 = ld<BF>(Wg, wbase + (size_t)(k+3) * I_DIM);
        float u0 = ld<BF>(Wu, wbase + (size_t)(k+0) * I_DIM);
        float u1 = ld<BF>(Wu, wbase + (size_t)(k+1) * I_DIM);
        float u2 = ld<BF>(Wu, wbase + (size_t)(k+2) * I_DIM);
        float u3 = ld<BF>(Wu, wbase + (size_t)(k+3) * I_DIM);
        #pragma unroll
        for (int tt = 0; tt < TT; ++tt) {
            float4 xv = *(const float4*)&xs[tt][k];
            ag[tt] = fmaf(xv.w, g3, fmaf(xv.z, g2, fmaf(xv.y, g1, fmaf(xv.x, g0, ag[tt]))));
            au[tt] = fmaf(xv.w, u3, fmaf(xv.z, u2, fmaf(xv.y, u1, fmaf(xv.x, u0, au[tt]))));
        }
    }
    float hval[TT];
    #pragma unroll
    for (int tt = 0; tt < TT; ++tt) {
        float g = ag[tt];
        hval[tt] = (g / (1.f + expf(-g))) * au[tt];
    }
    __syncthreads();
    #pragma unroll
    for (int tt = 0; tt < TT; ++tt) hs[tt][tid] = hval[tt];
    __syncthreads();

    size_t dbase = (size_t)e * I_DIM * O_DIM;
    float y0[TT], y1[TT];
    #pragma unroll
    for (int tt = 0; tt < TT; ++tt) { y0[tt] = 0.f; y1[tt] = 0.f; }

    for (int k = 0; k < I_DIM; k += 4) {
        float d00 = ld<BF>(Wd, dbase + (size_t)(k+0) * O_DIM + tid);
        float d01 = ld<BF>(Wd, dbase + (size_t)(k+1) * O_DIM + tid);
        float d02 = ld<BF>(Wd, dbase + (size_t)(k+2) * O_DIM + tid);
        float d03 = ld<BF>(Wd, dbase + (size_t)(k+3) * O_DIM + tid);
        float d10 = ld<BF>(Wd, dbase + (size_t)(k+0) * O_DIM + tid + 256);
        float d11 = ld<BF>(Wd, dbase + (size_t)(k+1) * O_DIM + tid + 256);
        float d12 = ld<BF>(Wd, dbase + (size_t)(k+2) * O_DIM + tid + 256);
        float d13 = ld<BF>(Wd, dbase + (size_t)(k+3) * O_DIM + tid + 256);
        #pragma unroll
        for (int tt = 0; tt < TT; ++tt) {
            float4 hv = *(const float4*)&hs[tt][k];
            y0[tt] = fmaf(hv.w, d03, fmaf(hv.z, d02, fmaf(hv.y, d01, fmaf(hv.x, d00, y0[tt]))));
            y1[tt] = fmaf(hv.w, d13, fmaf(hv.z, d12, fmaf(hv.y, d11, fmaf(hv.x, d10, y1[tt]))));
        }
    }

    int gsel = e >> 4;
    size_t colbase = (size_t)gsel * O_DIM;
    #pragma unroll
    for (int tt = 0; tt < TT; ++tt) {
        int it = t0 + tt;
        if (it < n) {
            float w  = wl[it];
            int tkn = tl[it];
            tkn = (tkn < 0) ? 0 : (tkn >= T_TOK ? T_TOK - 1 : tkn);
            atomicAdd(&z[(size_t)tkn * H_DIM + colbase + tid],       w * y0[tt]);
            atomicAdd(&z[(size_t)tkn * H_DIM + colbase + tid + 256], w * y1[tt]);
        }
    }
}

__global__ __launch_bounds__(256) void expert_kernel(
    const void* x, const void* Wg, const void* Wu, const void* Wd,
    const int* flag, const int* counts, const int* tok_list, const float* wt_list,
    float* z_fp32, float* z_bf16)
{
    if (*flag) expert_body<1>(x, Wg, Wu, Wd, counts, tok_list, wt_list, z_bf16);
    else       expert_body<0>(x, Wg, Wu, Wd, counts, tok_list, wt_list, z_fp32);
}

template<int BF>
__device__ void wc_body(const float* __restrict__ z, const void* __restrict__ Wc,
                        void* __restrict__ out_base)
{
    int t0  = blockIdx.x * WT;
    int tid = threadIdx.x;

    __shared__ __align__(16) float ps[WT][H_DIM];
    for (int idx = tid; idx < WT * H_DIM; idx += 256) {
        int tt = idx >> 10;
        int h  = idx & (H_DIM - 1);
        ps[tt][h] = z[(size_t)(t0 + tt) * H_DIM + h];
    }
    __syncthreads();

    float acc[WT][4];
    #pragma unroll
    for (int tt = 0; tt < WT; ++tt)
        #pragma unroll
        for (int qq = 0; qq < 4; ++qq) acc[tt][qq] = 0.f;

    for (int k = 0; k < H_DIM; k += 2) {
        float c00 = ld<BF>(Wc, (size_t)(k+0) * H_DIM + tid);
        float c01 = ld<BF>(Wc, (size_t)(k+0) * H_DIM + tid + 256);
        float c02 = ld<BF>(Wc, (size_t)(k+0) * H_DIM + tid + 512);
        float c03 = ld<BF>(Wc, (size_t)(k+0) * H_DIM + tid + 768);
        float c10 = ld<BF>(Wc, (size_t)(k+1) * H_DIM + tid);
        float c11 = ld<BF>(Wc, (size_t)(k+1) * H_DIM + tid + 256);
        float c12 = ld<BF>(Wc, (size_t)(k+1) * H_DIM + tid + 512);
        float c13 = ld<BF>(Wc, (size_t)(k+1) * H_DIM + tid + 768);
        #pragma unroll
        for (int tt = 0; tt < WT; ++tt) {
            float2 pv = *(const float2*)&ps[tt][k];
            acc[tt][0] = fmaf(pv.y, c10, fmaf(pv.x, c00, acc[tt][0]));
            acc[tt][1] = fmaf(pv.y, c11, fmaf(pv.x, c01, acc[tt][1]));
            acc[tt][2] = fmaf(pv.y, c12, fmaf(pv.x, c02, acc[tt][2]));
            acc[tt][3] = fmaf(pv.y, c13, fmaf(pv.x, c03, acc[tt][3]));
        }
    }

    #pragma unroll
    for (int tt = 0; tt < WT; ++tt) {
        #pragma unroll
        for (int qq = 0; qq < 4; ++qq) {
            size_t o = (size_t)(t0 + tt) * H_DIM + tid + 256 * qq;
            if (BF) ((hbf16*)out_base)[o] = __float2bfloat16(acc[tt][qq]);
            else    ((float*)out_base)[o] = acc[tt][qq];
        }
    }
}

__global__ __launch_bounds__(256) void wc_kernel(
    const float* z_fp32, const float* z_bf16, const void* Wc,
    void* out_base, const int* flag)
{
    if (*flag) wc_body<1>(z_bf16, Wc, out_base);
    else       wc_body<0>(z_fp32, Wc, out_base);
}

// ---------------------------------------------------------------------------
extern "C" void kernel_launch(void* const* d_in, const int* in_sizes, int n_in,
                              void* d_out, int out_size, void* d_ws, size_t ws_size,
                              hipStream_t stream)
{
    (void)in_sizes; (void)n_in; (void)out_size;

    const void* x  = d_in[0];
    const void* Wr = d_in[1];
    const void* Wg = d_in[2];
    const void* Wu = d_in[3];
    const void* Wd = d_in[4];
    const void* Wc = d_in[5];

    char* ws = (char*)d_ws;
    int*   counts   = (int*)(ws + 0);
    int*   flag     = (int*)(ws + 128);
    int*   tok_list = (int*)(ws + 4096);
    float* wt_list  = (float*)(ws + 4096 + (size_t)E_NUM * CAP * 4);

    detect_kernel<<<1, 256, 0, stream>>>((const uint32_t*)x, flag);

    if (ws_size >= ((size_t)58 << 20)) {
        float*  z    = (float*)(ws + ((size_t)1  << 20));   // 8 MB fp32
        ushort* Wg_t = (ushort*)(ws + ((size_t)16 << 20));  // 16 MB
        ushort* Wu_t = (ushort*)(ws + ((size_t)32 << 20));  // 16 MB
        ushort* Wd_t = (ushort*)(ws + ((size_t)48 << 20));  // 8 MB
        ushort* Wc_t = (ushort*)(ws + ((size_t)56 << 20));  // 2 MB

        zero_fast_kernel<<<2048, 256, 0, stream>>>(z, counts);
        convert_all_kernel<<<21504, 256, 0, stream>>>(Wg, Wu, Wd, Wc,
                                                      Wg_t, Wu_t, Wd_t, Wc_t, flag);
        router2_kernel<<<T_TOK / 8, 256, 0, stream>>>(x, Wr, d_out, flag,
                                                      counts, tok_list, wt_list);
        expert2_kernel<<<dim3(E_NUM, T_TOK / MT), 256, 0, stream>>>(
            x, Wg_t, Wu_t, Wd_t, flag, counts, tok_list, wt_list, z);
        wc2_kernel<<<dim3(T_TOK / MT, 4), 256, 0, stream>>>(z, Wc_t, d_out, flag);
    } else {
        float* z_bf16 = (float*)(ws + (1u << 20));
        float* z_fp32 = (float*)d_out;
        zero_kernel<<<T_TOK, 256, 0, stream>>>(z_fp32, z_bf16, flag, counts);
        router_kernel<<<T_TOK, 64, 0, stream>>>(x, Wr, d_out, flag, counts, tok_list, wt_list);
        expert_kernel<<<dim3(E_NUM, T_TOK / TT), 256, 0, stream>>>(
            x, Wg, Wu, Wd, flag, counts, tok_list, wt_list, z_fp32, z_bf16);
        wc_kernel<<<T_TOK / WT, 256, 0, stream>>>(z_fp32, z_bf16, Wc, d_out, flag);
    }
}

// Round 7
// 298.375 us; speedup vs baseline: 4.0852x; 1.0274x over previous
//
#include <hip/hip_runtime.h>
#include <hip/hip_bf16.h>
#include <math.h>
#include <stdint.h>

typedef __hip_bfloat16 hbf16;

#define T_TOK 2048
#define H_DIM 1024
#define E_NUM 32
#define I_DIM 256
#define O_DIM 512
#define CAP   2048
#define TT    16
#define WT    16
#define XSTR  1032   // xA/zA row stride in ushorts (1024 + 8 pad; 16B-aligned, 2-way banks)
#define HSTR  264    // hsm row stride in ushorts (256 + 8 pad)

typedef __bf16 bf16x8 __attribute__((ext_vector_type(8)));
typedef float  f32x4  __attribute__((ext_vector_type(4)));

__device__ __forceinline__ float b2f(hbf16 v) { return __bfloat162float(v); }
__device__ __forceinline__ float bb2f(ushort u) { return __uint_as_float((uint32_t)u << 16); }

__device__ __forceinline__ ushort f2b(float f) {   // fp32->bf16 RNE
    uint32_t u = __float_as_uint(f);
    return (ushort)((u + 0x7FFFu + ((u >> 16) & 1u)) >> 16);
}

template<int BF>
__device__ __forceinline__ float ld(const void* p, size_t i) {
    if (BF) return b2f(((const hbf16*)p)[i]);
    else    return ((const float*)p)[i];
}

__device__ __forceinline__ f32x4 mfma_bf16(bf16x8 a, bf16x8 b, f32x4 c) {
    return __builtin_amdgcn_mfma_f32_16x16x32_bf16(a, b, c, 0, 0, 0);
}

// ---------------------------------------------------------------------------
// detect: dtype flag + zero counts (counts needed before router)
// ---------------------------------------------------------------------------
__global__ __launch_bounds__(256) void detect_kernel(
    const uint32_t* __restrict__ xw, int* __restrict__ flag, int* __restrict__ counts)
{
    __shared__ int cnt;
    if (threadIdx.x == 0) cnt = 0;
    if (threadIdx.x < E_NUM) counts[threadIdx.x] = 0;
    __syncthreads();
    int c = 0;
    for (int i = threadIdx.x; i < 1024; i += 256) {
        int e = (xw[i] >> 7) & 0xFF;
        if (e >= 110 && e <= 140) c++;
    }
    atomicAdd(&cnt, c);
    __syncthreads();
    if (threadIdx.x == 0) *flag = (cnt > 512) ? 1 : 0;
}

// ===========================================================================
// FAST PATH (ws_size >= 58 MB)
// ===========================================================================

// ---- fused transpose+convert, 32(K) x 128(N) tiles, vectorized ----
__device__ void conv3_tile(const void* __restrict__ src, ushort* __restrict__ dst,
                           int bf, int K, int N, int b, float* __restrict__ sh)
{
    int tilesN = N >> 7, tilesK = K >> 5;
    int e  = b / (tilesK * tilesN);
    int r  = b % (tilesK * tilesN);
    int k0 = (r / tilesN) << 5;
    int n0 = (r % tilesN) << 7;
    size_t base = (size_t)e * K * N;
    int tid = threadIdx.x;
    {
        int row = tid >> 3, c0 = (tid & 7) * 16;
        if (!bf) {
            const float* sp = (const float*)src + base + (size_t)(k0 + row) * N + n0 + c0;
            #pragma unroll
            for (int i = 0; i < 4; ++i) {
                float4 v = *(const float4*)(sp + i * 4);
                sh[row * 132 + c0 + i*4 + 0] = v.x;
                sh[row * 132 + c0 + i*4 + 1] = v.y;
                sh[row * 132 + c0 + i*4 + 2] = v.z;
                sh[row * 132 + c0 + i*4 + 3] = v.w;
            }
        } else {
            const hbf16* sp = (const hbf16*)src + base + (size_t)(k0 + row) * N + n0 + c0;
            #pragma unroll
            for (int i = 0; i < 16; ++i) sh[row * 132 + c0 + i] = b2f(sp[i]);
        }
    }
    __syncthreads();
    {
        int nn = tid >> 1, kk = (tid & 1) * 16;
        union { ushort v[16]; uint4 u[2]; } R;
        #pragma unroll
        for (int i = 0; i < 16; ++i) R.v[i] = f2b(sh[(kk + i) * 132 + nn]);
        ushort* dp = dst + base + (size_t)(n0 + nn) * K + k0 + kk;
        *(uint4*)dp       = R.u[0];
        *(uint4*)(dp + 8) = R.u[1];
    }
    __syncthreads();   // sh reused if kernel loops (it doesn't) — cheap safety
}

__global__ __launch_bounds__(256) void convert_all_kernel(
    const void* Wg, const void* Wu, const void* Wd, const void* Wc,
    ushort* Wg_t, ushort* Wu_t, ushort* Wd_t, ushort* Wc_t,
    const int* __restrict__ flag)
{
    __shared__ float sh[32 * 132];
    int bf = *flag;
    int b = blockIdx.x;
    if      (b < 2048) conv3_tile(Wg, Wg_t, bf, 1024,  256, b,        sh);
    else if (b < 4096) conv3_tile(Wu, Wu_t, bf, 1024,  256, b - 2048, sh);
    else if (b < 5120) conv3_tile(Wd, Wd_t, bf,  256,  512, b - 4096, sh);
    else               conv3_tile(Wc, Wc_t, bf, 1024, 1024, b - 5120, sh);
}

// ---------------------------------------------------------------------------
// router3: 8 tokens/block, 256 blocks, LDS-tiled fp32 GEMM + selection.
// Writes tok_list entries packed: tok | (slot << 11).
// ---------------------------------------------------------------------------
template<int BF>
__device__ void router3_body(const void* __restrict__ x, const void* __restrict__ Wr,
                             void* __restrict__ out_base,
                             int* __restrict__ counts, int* __restrict__ tok_list,
                             float* __restrict__ wt_list,
                             float* __restrict__ xs, float* __restrict__ wrs,
                             float* __restrict__ sl)
{
    int tid = threadIdx.x;
    int t0  = blockIdx.x * 8;
    int e   = tid & 31;
    int ta  = tid >> 5;

    float acc = 0.f;
    for (int k0 = 0; k0 < H_DIM; k0 += 128) {
        __syncthreads();
        {
            int tr = tid >> 5, c = (tid & 31) * 4;
            if (!BF) {
                *(float4*)&xs[tr * 128 + c] = *(const float4*)((const float*)x +
                                              (size_t)(t0 + tr) * H_DIM + k0 + c);
            } else {
                const hbf16* xp = (const hbf16*)x + (size_t)(t0 + tr) * H_DIM + k0 + c;
                xs[tr*128+c+0] = b2f(xp[0]); xs[tr*128+c+1] = b2f(xp[1]);
                xs[tr*128+c+2] = b2f(xp[2]); xs[tr*128+c+3] = b2f(xp[3]);
            }
        }
        for (int i = tid; i < 1024; i += 256) {
            if (!BF) {
                ((float4*)wrs)[i] = *((const float4*)((const float*)Wr + (size_t)k0 * 32) + i);
            } else {
                const hbf16* wp = (const hbf16*)Wr + (size_t)k0 * 32 + i * 4;
                wrs[i*4+0] = b2f(wp[0]); wrs[i*4+1] = b2f(wp[1]);
                wrs[i*4+2] = b2f(wp[2]); wrs[i*4+3] = b2f(wp[3]);
            }
        }
        __syncthreads();
        #pragma unroll 8
        for (int k = 0; k < 128; k += 4) {
            float4 xv = *(const float4*)&xs[ta * 128 + k];
            float w0 = wrs[(k+0)*32 + e];
            float w1 = wrs[(k+1)*32 + e];
            float w2 = wrs[(k+2)*32 + e];
            float w3 = wrs[(k+3)*32 + e];
            acc = fmaf(xv.w, w3, fmaf(xv.z, w2, fmaf(xv.y, w1, fmaf(xv.x, w0, acc))));
        }
    }
    sl[ta * 32 + e] = acc;
    size_t li = (size_t)T_TOK * H_DIM + (size_t)(t0 + ta) * E_NUM + e;
    if (BF) ((hbf16*)out_base)[li] = __float2bfloat16(acc);
    else    ((float*)out_base)[li] = acc;
    __syncthreads();

    if (tid < 8) {
        int t = t0 + tid;
        float s[E_NUM];
        #pragma unroll
        for (int i = 0; i < E_NUM; ++i) s[i] = sl[tid * 32 + i];

        int   selE[4];
        float selL[4];
        int ns = 0;
        for (int g = 0; g < 2; ++g) {
            float sum0 = 0.f, sum1 = 0.f;
            #pragma unroll
            for (int j = 0; j < 8; ++j) {
                sum0 += s[(2*g)   * 8 + j];
                sum1 += s[(2*g+1) * 8 + j];
            }
            int bestSh = (sum1 > sum0) ? (2*g+1) : (2*g);
            int base = bestSh * 8;
            int i1 = 0;
            for (int j = 1; j < 8; ++j) if (s[base+j] > s[base+i1]) i1 = j;
            int i2 = -1;
            for (int j = 0; j < 8; ++j) {
                if (j == i1) continue;
                if (i2 < 0 || s[base+j] > s[base+i2]) i2 = j;
            }
            selE[ns] = base + i1; selL[ns] = s[base+i1]; ++ns;
            selE[ns] = base + i2; selL[ns] = s[base+i2]; ++ns;
        }
        float m = fmaxf(fmaxf(selL[0], selL[1]), fmaxf(selL[2], selL[3]));
        float w[4];
        float sum = 0.f;
        for (int j = 0; j < 4; ++j) { w[j] = expf(selL[j] - m); sum += w[j]; }
        float inv = 1.f / sum;
        for (int j = 0; j < 4; ++j) {
            int ee = selE[j];
            int pos = atomicAdd(&counts[ee], 1);
            if (pos >= 0 && pos < CAP) {
                tok_list[ee * CAP + pos] = t | (j << 11);   // pack slot
                wt_list[ee * CAP + pos]  = w[j] * inv;
            }
        }
    }
}

__global__ __launch_bounds__(256) void router3_kernel(
    const void* x, const void* Wr, void* out_base, const int* flag,
    int* counts, int* tok_list, float* wt_list)
{
    __shared__ float xs[8 * 128];
    __shared__ float wrs[128 * 32];
    __shared__ float sl[8 * 32];
    if (*flag) router3_body<1>(x, Wr, out_base, counts, tok_list, wt_list, xs, wrs, sl);
    else       router3_body<0>(x, Wr, out_base, counts, tok_list, wt_list, xs, wrs, sl);
}

// ---------------------------------------------------------------------------
// expert3: 512 thr (8 waves), M=32 tokens/block, grid (32, 64).
// x staged once (full K=1024, bf16, single buffer). Gate/up N=256 (32 cols/
// wave, j=0..1); down N=512 (64 cols/wave, j=0..3). Register-dbuf B groups.
// Output: y = w*down stored bf16 to ybuf[t][slot][512] (no atomics).
// ---------------------------------------------------------------------------
template<int BF>
__device__ void expert3_body(const void* __restrict__ x,
    const ushort* __restrict__ Wg_t, const ushort* __restrict__ Wu_t,
    const ushort* __restrict__ Wd_t,
    const int* __restrict__ counts, const int* __restrict__ tok_list,
    const float* __restrict__ wt_list, ushort* __restrict__ ybuf,
    ushort* __restrict__ xA, ushort* __restrict__ hsm,
    int* __restrict__ tokid, float* __restrict__ twt, int* __restrict__ tslot)
{
    int e = blockIdx.x;
    int n = counts[e]; n = n < 0 ? 0 : (n > CAP ? CAP : n);
    int t0 = blockIdx.y * 32;
    if (t0 >= n) return;
    int tid  = threadIdx.x;
    int lane = tid & 63, wv = tid >> 6;        // wv 0..7
    int q = lane >> 4, l15 = lane & 15;

    if (tid < 32) {
        int it = t0 + tid;
        int id; float ww;
        if (it < n) { id = tok_list[e*CAP + it]; ww = wt_list[e*CAP + it]; }
        else        { id = tok_list[e*CAP + t0]; ww = 0.f; }
        tokid[tid] = id & 2047;
        tslot[tid] = (id >> 11) & 3;
        twt[tid]   = ww;
    }
    __syncthreads();

    // ---- stage x[32][1024] -> bf16 LDS ----
    {
        int row = tid >> 4;
        int kb  = (tid & 15) * 8;
        size_t srow = (size_t)tokid[row] * H_DIM;
        #pragma unroll
        for (int c = 0; c < 8; ++c) {
            int k = kb + c * 128;
            union { ushort v[8]; uint4 u; } U;
            if (BF) {
                U.u = *(const uint4*)((const ushort*)x + srow + k);
            } else {
                const float* xp = (const float*)x + srow + k;
                float4 a = *(const float4*)xp;
                float4 b = *(const float4*)(xp + 4);
                U.v[0]=f2b(a.x); U.v[1]=f2b(a.y); U.v[2]=f2b(a.z); U.v[3]=f2b(a.w);
                U.v[4]=f2b(b.x); U.v[5]=f2b(b.y); U.v[6]=f2b(b.z); U.v[7]=f2b(b.w);
            }
            *(uint4*)&xA[row * XSTR + k] = U.u;
        }
    }
    __syncthreads();

    // ---- gate/up: K=1024 = 8 groups x 4 idx(K=32) ----
    const ushort* BgP = Wg_t + ((size_t)e * I_DIM + wv*32 + l15) * H_DIM + q*8;
    const ushort* BuP = Wu_t + ((size_t)e * I_DIM + wv*32 + l15) * H_DIM + q*8;

    f32x4 Cg[2][2], Cu[2][2];
    #pragma unroll
    for (int m = 0; m < 2; ++m)
        #pragma unroll
        for (int j = 0; j < 2; ++j) { Cg[m][j] = (f32x4)0.f; Cu[m][j] = (f32x4)0.f; }

    bf16x8 bg[2][4][2], bu[2][4][2];
    #pragma unroll
    for (int ig = 0; ig < 4; ++ig)
        #pragma unroll
        for (int j = 0; j < 2; ++j) {
            bg[0][ig][j] = *(const bf16x8*)(BgP + (size_t)j*16*H_DIM + ig*32);
            bu[0][ig][j] = *(const bf16x8*)(BuP + (size_t)j*16*H_DIM + ig*32);
        }

    #pragma unroll
    for (int grp = 0; grp < 8; ++grp) {
        int cb = grp & 1;
        if (grp < 7) {
            #pragma unroll
            for (int ig = 0; ig < 4; ++ig)
                #pragma unroll
                for (int j = 0; j < 2; ++j) {
                    int idx = (grp + 1) * 4 + ig;
                    bg[cb^1][ig][j] = *(const bf16x8*)(BgP + (size_t)j*16*H_DIM + idx*32);
                    bu[cb^1][ig][j] = *(const bf16x8*)(BuP + (size_t)j*16*H_DIM + idx*32);
                }
        }
        #pragma unroll
        for (int ig = 0; ig < 4; ++ig) {
            int idx = grp * 4 + ig;
            bf16x8 A0 = *(const bf16x8*)&xA[(l15)      * XSTR + idx*32 + q*8];
            bf16x8 A1 = *(const bf16x8*)&xA[(16 + l15) * XSTR + idx*32 + q*8];
            #pragma unroll
            for (int j = 0; j < 2; ++j) {
                Cg[0][j] = mfma_bf16(A0, bg[cb][ig][j], Cg[0][j]);
                Cg[1][j] = mfma_bf16(A1, bg[cb][ig][j], Cg[1][j]);
                Cu[0][j] = mfma_bf16(A0, bu[cb][ig][j], Cu[0][j]);
                Cu[1][j] = mfma_bf16(A1, bu[cb][ig][j], Cu[1][j]);
            }
        }
    }

    // ---- h = silu(g)*u -> hsm ----
    #pragma unroll
    for (int m = 0; m < 2; ++m)
        #pragma unroll
        for (int j = 0; j < 2; ++j)
            #pragma unroll
            for (int r = 0; r < 4; ++r) {
                float g = Cg[m][j][r], u = Cu[m][j][r];
                float h = (g / (1.f + expf(-g))) * u;
                hsm[(m*16 + q*4 + r) * HSTR + wv*32 + j*16 + l15] = f2b(h);
            }
    __syncthreads();

    // ---- down: K=256 = 8 kc; preload all 32 B frags (2 groups) ----
    const ushort* BdP = Wd_t + ((size_t)e * O_DIM + wv*64 + l15) * I_DIM + q*8;
    f32x4 Cd[2][4];
    #pragma unroll
    for (int m = 0; m < 2; ++m)
        #pragma unroll
        for (int j = 0; j < 4; ++j) Cd[m][j] = (f32x4)0.f;

    bf16x8 bd[2][4][4];
    #pragma unroll
    for (int g2 = 0; g2 < 2; ++g2)
        #pragma unroll
        for (int kc2 = 0; kc2 < 4; ++kc2)
            #pragma unroll
            for (int j = 0; j < 4; ++j)
                bd[g2][kc2][j] = *(const bf16x8*)(BdP + (size_t)j*16*I_DIM + (g2*4 + kc2)*32);

    #pragma unroll
    for (int g2 = 0; g2 < 2; ++g2)
        #pragma unroll
        for (int kc2 = 0; kc2 < 4; ++kc2) {
            int kc = g2 * 4 + kc2;
            bf16x8 A0 = *(const bf16x8*)&hsm[(l15)      * HSTR + kc*32 + q*8];
            bf16x8 A1 = *(const bf16x8*)&hsm[(16 + l15) * HSTR + kc*32 + q*8];
            #pragma unroll
            for (int j = 0; j < 4; ++j) {
                Cd[0][j] = mfma_bf16(A0, bd[g2][kc2][j], Cd[0][j]);
                Cd[1][j] = mfma_bf16(A1, bd[g2][kc2][j], Cd[1][j]);
            }
        }

    // ---- store y = w * down to ybuf[t][slot][col], bf16, guarded ----
    #pragma unroll
    for (int m = 0; m < 2; ++m)
        #pragma unroll
        for (int r = 0; r < 4; ++r) {
            int row = m*16 + q*4 + r;
            if (t0 + row < n) {
                float ww = twt[row];
                size_t base = ((size_t)tokid[row] * 4 + tslot[row]) * O_DIM;
                #pragma unroll
                for (int j = 0; j < 4; ++j)
                    ybuf[base + wv*64 + j*16 + l15] = f2b(ww * Cd[m][j][r]);
            }
        }
}

__global__ __launch_bounds__(512, 2) void expert3_kernel(
    const void* x, const ushort* Wg_t, const ushort* Wu_t, const ushort* Wd_t,
    const int* flag, const int* counts, const int* tok_list, const float* wt_list,
    ushort* ybuf)
{
    __shared__ ushort xA[32 * XSTR];
    __shared__ ushort hsm[32 * HSTR];
    __shared__ int    tokid[32];
    __shared__ float  twt[32];
    __shared__ int    tslot[32];
    if (*flag) expert3_body<1>(x, Wg_t, Wu_t, Wd_t, counts, tok_list, wt_list,
                               ybuf, xA, hsm, tokid, twt, tslot);
    else       expert3_body<0>(x, Wg_t, Wu_t, Wd_t, counts, tok_list, wt_list,
                               ybuf, xA, hsm, tokid, twt, tslot);
}

// ---------------------------------------------------------------------------
// wc3: out = z @ Wc with z rows built from ybuf slot sums. 512 thr, M=32,
// N=256, grid (64, 4).
// ---------------------------------------------------------------------------
template<int BF>
__device__ void wc3_body(const ushort* __restrict__ ybuf, const ushort* __restrict__ Wc_t,
                         void* __restrict__ out_base, ushort* __restrict__ zA)
{
    int m0  = blockIdx.x * 32;
    int n0  = blockIdx.y * 256;
    int tid = threadIdx.x;
    int lane = tid & 63, wv = tid >> 6;
    int q = lane >> 4, l15 = lane & 15;

    // ---- stage z[32][1024] = slot-pair sums, bf16 ----
    {
        int row = tid >> 4;
        int kb  = (tid & 15) * 8;
        int t = m0 + row;
        #pragma unroll
        for (int c = 0; c < 8; ++c) {
            int h  = kb + c * 128;
            int s0 = (h < 512) ? 0 : 2;
            int hh = (h < 512) ? h : (h - 512);
            const ushort* p0 = ybuf + ((size_t)t * 4 + s0) * O_DIM + hh;
            union { ushort v[8]; uint4 u; } A, B, R;
            A.u = *(const uint4*)p0;
            B.u = *(const uint4*)(p0 + O_DIM);
            #pragma unroll
            for (int i = 0; i < 8; ++i) R.v[i] = f2b(bb2f(A.v[i]) + bb2f(B.v[i]));
            *(uint4*)&zA[row * XSTR + h] = R.u;
        }
    }
    __syncthreads();

    const ushort* BcP = Wc_t + ((size_t)(n0 + wv*32 + l15)) * H_DIM + q*8;
    f32x4 C[2][2];
    #pragma unroll
    for (int m = 0; m < 2; ++m)
        #pragma unroll
        for (int j = 0; j < 2; ++j) C[m][j] = (f32x4)0.f;

    bf16x8 bc[2][4][2];
    #pragma unroll
    for (int ig = 0; ig < 4; ++ig)
        #pragma unroll
        for (int j = 0; j < 2; ++j)
            bc[0][ig][j] = *(const bf16x8*)(BcP + (size_t)j*16*H_DIM + ig*32);

    #pragma unroll
    for (int grp = 0; grp < 8; ++grp) {
        int cb = grp & 1;
        if (grp < 7) {
            #pragma unroll
            for (int ig = 0; ig < 4; ++ig)
                #pragma unroll
                for (int j = 0; j < 2; ++j) {
                    int idx = (grp + 1) * 4 + ig;
                    bc[cb^1][ig][j] = *(const bf16x8*)(BcP + (size_t)j*16*H_DIM + idx*32);
                }
        }
        #pragma unroll
        for (int ig = 0; ig < 4; ++ig) {
            int idx = grp * 4 + ig;
            bf16x8 A0 = *(const bf16x8*)&zA[(l15)      * XSTR + idx*32 + q*8];
            bf16x8 A1 = *(const bf16x8*)&zA[(16 + l15) * XSTR + idx*32 + q*8];
            #pragma unroll
            for (int j = 0; j < 2; ++j) {
                C[0][j] = mfma_bf16(A0, bc[cb][ig][j], C[0][j]);
                C[1][j] = mfma_bf16(A1, bc[cb][ig][j], C[1][j]);
            }
        }
    }

    #pragma unroll
    for (int m = 0; m < 2; ++m)
        #pragma unroll
        for (int j = 0; j < 2; ++j)
            #pragma unroll
            for (int r = 0; r < 4; ++r) {
                int row = m0 + m*16 + q*4 + r;
                int col = n0 + wv*32 + j*16 + l15;
                size_t o = (size_t)row * H_DIM + col;
                if (BF) ((hbf16*)out_base)[o] = __float2bfloat16(C[m][j][r]);
                else    ((float*)out_base)[o] = C[m][j][r];
            }
}

__global__ __launch_bounds__(512, 2) void wc3_kernel(
    const ushort* ybuf, const ushort* Wc_t, void* out_base, const int* flag)
{
    __shared__ ushort zA[32 * XSTR];
    if (*flag) wc3_body<1>(ybuf, Wc_t, out_base, zA);
    else       wc3_body<0>(ybuf, Wc_t, out_base, zA);
}

// ===========================================================================
// FALLBACK PATH (round-4, known passing) — only if ws is small
// ===========================================================================

__global__ __launch_bounds__(256) void zero_kernel(
    float* __restrict__ z_fp32, float* __restrict__ z_bf16,
    const int* __restrict__ flag, int* __restrict__ counts)
{
    float* base = (*flag) ? z_bf16 : z_fp32;
    size_t i = (size_t)blockIdx.x * 256 + threadIdx.x;
    ((float4*)base)[i] = make_float4(0.f, 0.f, 0.f, 0.f);
    if (blockIdx.x == 0 && threadIdx.x < E_NUM) counts[threadIdx.x] = 0;
}

template<int BF>
__device__ void router_body(const void* __restrict__ x, const void* __restrict__ Wr,
                            void* __restrict__ out_base,
                            int* __restrict__ counts, int* __restrict__ tok_list,
                            float* __restrict__ wt_list, float* __restrict__ sl)
{
    int t    = blockIdx.x;
    int lane = threadIdx.x;
    int e    = lane & 31;
    int half = lane >> 5;

    float acc = 0.f;
    size_t xoff = (size_t)t * H_DIM;
    int h0 = half * (H_DIM / 2);
    for (int h = h0; h < h0 + H_DIM / 2; ++h)
        acc = fmaf(ld<BF>(x, xoff + h), ld<BF>(Wr, (size_t)h * E_NUM + e), acc);
    acc += __shfl_down(acc, 32);

    if (lane < 32) {
        sl[e] = acc;
        size_t li = (size_t)T_TOK * H_DIM + (size_t)t * E_NUM + e;
        if (BF) ((hbf16*)out_base)[li] = __float2bfloat16(acc);
        else    ((float*)out_base)[li] = acc;
    }
    __syncthreads();

    if (lane == 0) {
        float s[E_NUM];
        #pragma unroll
        for (int i = 0; i < E_NUM; ++i) s[i] = sl[i];
        int   selE[4];
        float selL[4];
        int ns = 0;
        for (int g = 0; g < 2; ++g) {
            float sum0 = 0.f, sum1 = 0.f;
            #pragma unroll
            for (int j = 0; j < 8; ++j) {
                sum0 += s[(2*g)   * 8 + j];
                sum1 += s[(2*g+1) * 8 + j];
            }
            int bestSh = (sum1 > sum0) ? (2*g+1) : (2*g);
            int base = bestSh * 8;
            int i1 = 0;
            for (int j = 1; j < 8; ++j) if (s[base+j] > s[base+i1]) i1 = j;
            int i2 = -1;
            for (int j = 0; j < 8; ++j) {
                if (j == i1) continue;
                if (i2 < 0 || s[base+j] > s[base+i2]) i2 = j;
            }
            selE[ns] = base + i1; selL[ns] = s[base+i1]; ++ns;
            selE[ns] = base + i2; selL[ns] = s[base+i2]; ++ns;
        }
        float m = fmaxf(fmaxf(selL[0], selL[1]), fmaxf(selL[2], selL[3]));
        float w[4];
        float sum = 0.f;
        for (int j = 0; j < 4; ++j) { w[j] = expf(selL[j] - m); sum += w[j]; }
        float inv = 1.f / sum;
        for (int j = 0; j < 4; ++j) {
            int ee = selE[j];
            int pos = atomicAdd(&counts[ee], 1);
            if (pos >= 0 && pos < CAP) {
                tok_list[ee * CAP + pos] = t;
                wt_list[ee * CAP + pos]  = w[j] * inv;
            }
        }
    }
}

__global__ __launch_bounds__(64) void router_kernel(
    const void* x, const void* Wr, void* out_base, const int* flag,
    int* counts, int* tok_list, float* wt_list)
{
    __shared__ float sl[E_NUM];
    if (*flag) router_body<1>(x, Wr, out_base, counts, tok_list, wt_list, sl);
    else       router_body<0>(x, Wr, out_base, counts, tok_list, wt_list, sl);
}

template<int BF>
__device__ void expert_body(const void* __restrict__ x,
                            const void* __restrict__ Wg, const void* __restrict__ Wu,
                            const void* __restrict__ Wd,
                            const int* __restrict__ counts, const int* __restrict__ tok_list,
                            const float* __restrict__ wt_list,
                            float* __restrict__ z, float* __restrict__ xsbuf)
{
    int e = blockIdx.x;
    int n = counts[e];
    n = n < 0 ? 0 : (n > CAP ? CAP : n);
    int t0 = blockIdx.y * TT;
    if (t0 >= n) return;
    int tid = threadIdx.x;

    float (*xs)[H_DIM] = reinterpret_cast<float(*)[H_DIM]>(xsbuf);
    float (*hs)[I_DIM] = reinterpret_cast<float(*)[I_DIM]>(xsbuf);

    const int*   tl = tok_list + e * CAP;
    const float* wl = wt_list  + e * CAP;

    for (int idx = tid; idx < TT * H_DIM; idx += 256) {
        int tt = idx >> 10;
        int h  = idx & (H_DIM - 1);
        int it = t0 + tt;
        int tkn = (it < n) ? tl[it] : tl[t0];
        tkn = (tkn < 0) ? 0 : (tkn >= T_TOK ? T_TOK - 1 : tkn);
        xs[tt][h] = ld<BF>(x, (size_t)tkn * H_DIM + h);
    }
    __syncthreads();

    size_t wbase = (size_t)e * H_DIM * I_DIM + tid;
    float ag[TT], au[TT];
    #pragma unroll
    for (int tt = 0; tt < TT; ++tt) { ag[tt] = 0.f; au[tt] = 0.f; }

    for (int k = 0; k < H_DIM; k += 4) {
        float g0 = ld<BF>(Wg, wbase + (size_t)(k+0) * I_DIM);
        float g1 = ld<BF>(Wg, wbase + (size_t)(k+1) * I_DIM);
        float g2 = ld<BF>(Wg, wbase + (size_t)(k+2) * I_DIM);
        float g3 = ld<BF>(Wg, wbase + (size_t)(k+3) * I_DIM);
        float u0 = ld<BF>(Wu, wbase + (size_t)(k+0) * I_DIM);
        float u1 = ld<BF>(Wu, wbase + (size_t)(k+1) * I_DIM);
        float u2 = ld<BF>(Wu, wbase + (size_t)(k+2) * I_DIM);
        float u3 = ld<BF>(Wu, wbase + (size_t)(k+3) * I_DIM);
        #pragma unroll
        for (int tt = 0; tt < TT; ++tt) {
            float4 xv = *(const float4*)&xs[tt][k];
            ag[tt] = fmaf(xv.w, g3, fmaf(xv.z, g2, fmaf(xv.y, g1, fmaf(xv.x, g0, ag[tt]))));
            au[tt] = fmaf(xv.w, u3, fmaf(xv.z, u2, fmaf(xv.y, u1, fmaf(xv.x, u0, au[tt]))));
        }
    }
    float hval[TT];
    #pragma unroll
    for (int tt = 0; tt < TT; ++tt) {
        float g = ag[tt];
        hval[tt] = (g / (1.f + expf(-g))) * au[tt];
    }
    __syncthreads();
    #pragma unroll
    for (int tt = 0; tt < TT; ++tt) hs[tt][tid] = hval[tt];
    __syncthreads();

    size_t dbase = (size_t)e * I_DIM * O_DIM;
    float y0[TT], y1[TT];
    #pragma unroll
    for (int tt = 0; tt < TT; ++tt) { y0[tt] = 0.f; y1[tt] = 0.f; }

    for (int k = 0; k < I_DIM; k += 4) {
        float d00 = ld<BF>(Wd, dbase + (size_t)(k+0) * O_DIM + tid);
        float d01 = ld<BF>(Wd, dbase + (size_t)(k+1) * O_DIM + tid);
        float d02 = ld<BF>(Wd, dbase + (size_t)(k+2) * O_DIM + tid);
        float d03 = ld<BF>(Wd, dbase + (size_t)(k+3) * O_DIM + tid);
        float d10 = ld<BF>(Wd, dbase + (size_t)(k+0) * O_DIM + tid + 256);
        float d11 = ld<BF>(Wd, dbase + (size_t)(k+1) * O_DIM + tid + 256);
        float d12 = ld<BF>(Wd, dbase + (size_t)(k+2) * O_DIM + tid + 256);
        float d13 = ld<BF>(Wd, dbase + (size_t)(k+3) * O_DIM + tid + 256);
        #pragma unroll
        for (int tt = 0; tt < TT; ++tt) {
            float4 hv = *(const float4*)&hs[tt][k];
            y0[tt] = fmaf(hv.w, d03, fmaf(hv.z, d02, fmaf(hv.y, d01, fmaf(hv.x, d00, y0[tt]))));
            y1[tt] = fmaf(hv.w, d13, fmaf(hv.z, d12, fmaf(hv.y, d11, fmaf(hv.x, d10, y1[tt]))));
        }
    }

    int gsel = e >> 4;
    size_t colbase = (size_t)gsel * O_DIM;
    #pragma unroll
    for (int tt = 0; tt < TT; ++tt) {
        int it = t0 + tt;
        if (it < n) {
            float w  = wl[it];
            int tkn = tl[it];
            tkn = (tkn < 0) ? 0 : (tkn >= T_TOK ? T_TOK - 1 : tkn);
            atomicAdd(&z[(size_t)tkn * H_DIM + colbase + tid],       w * y0[tt]);
            atomicAdd(&z[(size_t)tkn * H_DIM + colbase + tid + 256], w * y1[tt]);
        }
    }
}

__global__ __launch_bounds__(256) void expert_kernel(
    const void* x, const void* Wg, const void* Wu, const void* Wd,
    const int* flag, const int* counts, const int* tok_list, const float* wt_list,
    float* z_fp32, float* z_bf16)
{
    __shared__ __align__(16) float xsbuf[TT * H_DIM];
    if (*flag) expert_body<1>(x, Wg, Wu, Wd, counts, tok_list, wt_list, z_bf16, xsbuf);
    else       expert_body<0>(x, Wg, Wu, Wd, counts, tok_list, wt_list, z_fp32, xsbuf);
}

template<int BF>
__device__ void wc_body(const float* __restrict__ z, const void* __restrict__ Wc,
                        void* __restrict__ out_base, float* __restrict__ psbuf)
{
    int t0  = blockIdx.x * WT;
    int tid = threadIdx.x;
    float (*ps)[H_DIM] = reinterpret_cast<float(*)[H_DIM]>(psbuf);

    for (int idx = tid; idx < WT * H_DIM; idx += 256) {
        int tt = idx >> 10;
        int h  = idx & (H_DIM - 1);
        ps[tt][h] = z[(size_t)(t0 + tt) * H_DIM + h];
    }
    __syncthreads();

    float acc[WT][4];
    #pragma unroll
    for (int tt = 0; tt < WT; ++tt)
        #pragma unroll
        for (int qq = 0; qq < 4; ++qq) acc[tt][qq] = 0.f;

    for (int k = 0; k < H_DIM; k += 2) {
        float c00 = ld<BF>(Wc, (size_t)(k+0) * H_DIM + tid);
        float c01 = ld<BF>(Wc, (size_t)(k+0) * H_DIM + tid + 256);
        float c02 = ld<BF>(Wc, (size_t)(k+0) * H_DIM + tid + 512);
        float c03 = ld<BF>(Wc, (size_t)(k+0) * H_DIM + tid + 768);
        float c10 = ld<BF>(Wc, (size_t)(k+1) * H_DIM + tid);
        float c11 = ld<BF>(Wc, (size_t)(k+1) * H_DIM + tid + 256);
        float c12 = ld<BF>(Wc, (size_t)(k+1) * H_DIM + tid + 512);
        float c13 = ld<BF>(Wc, (size_t)(k+1) * H_DIM + tid + 768);
        #pragma unroll
        for (int tt = 0; tt < WT; ++tt) {
            float2 pv = *(const float2*)&ps[tt][k];
            acc[tt][0] = fmaf(pv.y, c10, fmaf(pv.x, c00, acc[tt][0]));
            acc[tt][1] = fmaf(pv.y, c11, fmaf(pv.x, c01, acc[tt][1]));
            acc[tt][2] = fmaf(pv.y, c12, fmaf(pv.x, c02, acc[tt][2]));
            acc[tt][3] = fmaf(pv.y, c13, fmaf(pv.x, c03, acc[tt][3]));
        }
    }

    #pragma unroll
    for (int tt = 0; tt < WT; ++tt) {
        #pragma unroll
        for (int qq = 0; qq < 4; ++qq) {
            size_t o = (size_t)(t0 + tt) * H_DIM + tid + 256 * qq;
            if (BF) ((hbf16*)out_base)[o] = __float2bfloat16(acc[tt][qq]);
            else    ((float*)out_base)[o] = acc[tt][qq];
        }
    }
}

__global__ __launch_bounds__(256) void wc_kernel(
    const float* z_fp32, const float* z_bf16, const void* Wc,
    void* out_base, const int* flag)
{
    __shared__ __align__(16) float psbuf[WT * H_DIM];
    if (*flag) wc_body<1>(z_bf16, Wc, out_base, psbuf);
    else       wc_body<0>(z_fp32, Wc, out_base, psbuf);
}

// ---------------------------------------------------------------------------
extern "C" void kernel_launch(void* const* d_in, const int* in_sizes, int n_in,
                              void* d_out, int out_size, void* d_ws, size_t ws_size,
                              hipStream_t stream)
{
    (void)in_sizes; (void)n_in; (void)out_size;

    const void* x  = d_in[0];
    const void* Wr = d_in[1];
    const void* Wg = d_in[2];
    const void* Wu = d_in[3];
    const void* Wd = d_in[4];
    const void* Wc = d_in[5];

    char* ws = (char*)d_ws;
    int*   counts   = (int*)(ws + 0);
    int*   flag     = (int*)(ws + 128);
    int*   tok_list = (int*)(ws + 4096);
    float* wt_list  = (float*)(ws + 4096 + (size_t)E_NUM * CAP * 4);

    detect_kernel<<<1, 256, 0, stream>>>((const uint32_t*)x, flag, counts);

    if (ws_size >= ((size_t)58 << 20)) {
        ushort* ybuf = (ushort*)(ws + ((size_t)1  << 20));  // 8 MB bf16 [T][4][512]
        ushort* Wg_t = (ushort*)(ws + ((size_t)16 << 20));  // 16 MB
        ushort* Wu_t = (ushort*)(ws + ((size_t)32 << 20));  // 16 MB
        ushort* Wd_t = (ushort*)(ws + ((size_t)48 << 20));  // 8 MB
        ushort* Wc_t = (ushort*)(ws + ((size_t)56 << 20));  // 2 MB

        convert_all_kernel<<<5376, 256, 0, stream>>>(Wg, Wu, Wd, Wc,
                                                     Wg_t, Wu_t, Wd_t, Wc_t, flag);
        router3_kernel<<<T_TOK / 8, 256, 0, stream>>>(x, Wr, d_out, flag,
                                                      counts, tok_list, wt_list);
        expert3_kernel<<<dim3(E_NUM, T_TOK / 32), 512, 0, stream>>>(
            x, Wg_t, Wu_t, Wd_t, flag, counts, tok_list, wt_list, ybuf);
        wc3_kernel<<<dim3(T_TOK / 32, 4), 512, 0, stream>>>(ybuf, Wc_t, d_out, flag);
    } else {
        float* z_bf16 = (float*)(ws + (1u << 20));
        float* z_fp32 = (float*)d_out;
        zero_kernel<<<T_TOK, 256, 0, stream>>>(z_fp32, z_bf16, flag, counts);
        router_kernel<<<T_TOK, 64, 0, stream>>>(x, Wr, d_out, flag, counts, tok_list, wt_list);
        expert_kernel<<<dim3(E_NUM, T_TOK / TT), 256, 0, stream>>>(
            x, Wg, Wu, Wd, flag, counts, tok_list, wt_list, z_fp32, z_bf16);
        wc_kernel<<<T_TOK / WT, 256, 0, stream>>>(z_fp32, z_bf16, Wc, d_out, flag);
    }
}